// Round 13
// baseline (2221.611 us; speedup 1.0000x reference)
//
#include <hip/hip_runtime.h>
#include <hip/hip_bf16.h>
#include <cstddef>

typedef __hip_bfloat16 bf16;
typedef short short8 __attribute__((ext_vector_type(8)));
typedef short short4v __attribute__((ext_vector_type(4)));
typedef float float4v __attribute__((ext_vector_type(4)));
#define DEV static __device__ __forceinline__

constexpr int NB = 16;     // batch
constexpr int SEQL = 20;
constexpr int CD = 256;    // VD
constexpr int PP = 1024;   // 32*32
constexpr int HND = 512;
constexpr int EMBD = 300;
constexpr int CIN = 776;   // 256 + 8 + 512

// ---- workspace layout (float element offsets); bf16 buffers are [n][p][c] ----
constexpr size_t SZB = (size_t)NB * PP * CD / 2;             // floats per bf16 NPC buffer
constexpr size_t OF_FEATB = 0;                               // running feature (bf16)
constexpr size_t OF_TB   = 1*SZB;                            // t (bf16)
constexpr size_t OF_KHB  = 2*SZB;                            // kh (bf16)
constexpr size_t OF_VVB  = 3*SZB;                            // vv (bf16)
constexpr size_t OF_QH   = 7*SZB;                            // qh [s][n][c] fp32
constexpr size_t OF_HNW  = OF_QH  + (size_t)SEQL*NB*CD;      // hnW [r][n][o] fp32
constexpr size_t OF_SCV  = OF_HNW + (size_t)9*NB*CD;         // sconv [p][o] fp32
constexpr size_t OF_WRG  = OF_SCV + (size_t)PP*CD;           // W_region [r][o][c] fp32
constexpr size_t OF_AW   = OF_WRG + (size_t)9*CD*HND;        // conv W A-frags (589,824 bf16)
constexpr size_t OF_PK   = OF_AW  + (size_t)294912;          // linear W B-frags: 5 x 65,536 bf16
constexpr size_t OF_FLAG = OF_PK  + (size_t)163840;          // dtype flag

DEV float bf2f(bf16 v) { return __bfloat162float(v); }
DEV bf16 f2bf(float v) { return __float2bfloat16(v); }
DEV float sh2f(short v) { bf16 t; *(short*)&t = v; return __bfloat162float(t); }
DEV short f2sh(float v) { bf16 t = f2bf(v); return *(const short*)&t; }

DEV float LD(const void* p, size_t i, int bf) {
  return bf ? __bfloat162float(((const bf16*)p)[i]) : ((const float*)p)[i];
}
DEV int get_bf(const float* ws) { return ((const int*)ws)[OF_FLAG]; }

__global__ void k_detect(const void* g, float* ws) {
  if (threadIdx.x == 0 && blockIdx.x == 0) {
    unsigned w = *(const unsigned*)g;
    ((int*)ws)[OF_FLAG] = ((w & 0xFFFFu) != 0u) ? 1 : 0;
  }
}

// LN reduction, 512 threads: tile[o][x] stride 33; red[1024+x]=mean, red[1056+x]=rstd
// NOTE (R9 lesson): do NOT replace with __shfl chains — shfl = ds_swizzle (LDS pipe).
DEV void ln_reduce512(const float* tile, float* red, int tid) {
  const int x = tid & 31, seg = tid >> 5;   // 16 segs of 16 channels
  float s = 0.f, sq = 0.f;
#pragma unroll
  for (int i = 0; i < 16; ++i) {
    float v = tile[(seg*16 + i)*33 + x];
    s += v; sq += v*v;
  }
  red[seg*32 + x] = s;
  red[512 + seg*32 + x] = sq;
  __syncthreads();
  if (tid < 32) {
    float ts = 0.f, tq = 0.f;
#pragma unroll
    for (int g = 0; g < 16; ++g) { ts += red[g*32 + tid]; tq += red[512 + g*32 + tid]; }
    float m = ts * (1.f/CD);
    float var = tq * (1.f/CD) - m*m;
    red[1024 + tid] = m;
    red[1056 + tid] = 1.f / sqrtf(var + 1e-5f);
  }
  __syncthreads();
}

// 512-thr linear core: ALL 16 global B-frags preloaded up front.
// Layout (production-validated): A m=lane&15, k=(lane>>4)*8+j; B n=lane&15, same k;
// D m=(lane>>4)*4+r, n=lane&15.
DEV void mfma_core512(const short* __restrict__ As, const short* __restrict__ PKg,
                      int w, int lane, float4v acc[2][2]) {
  const int xb = lane & 15, quad = lane >> 4;
  const short* base = PKg + lane*8;
  short8 b0[8], b1[8];
#pragma unroll
  for (int ch = 0; ch < 8; ++ch) {
    b0[ch] = *(const short8*)&base[(size_t)((w*2+0)*8 + ch)*512];
    b1[ch] = *(const short8*)&base[(size_t)((w*2+1)*8 + ch)*512];
  }
#pragma unroll
  for (int ch = 0; ch < 8; ++ch) {
    short8 a0 = *(const short8*)&As[xb*264 + ch*32 + quad*8];
    short8 a1 = *(const short8*)&As[(16+xb)*264 + ch*32 + quad*8];
    acc[0][0] = __builtin_amdgcn_mfma_f32_16x16x32_bf16(a0, b0[ch], acc[0][0], 0, 0, 0);
    acc[0][1] = __builtin_amdgcn_mfma_f32_16x16x32_bf16(a0, b1[ch], acc[0][1], 0, 0, 0);
    acc[1][0] = __builtin_amdgcn_mfma_f32_16x16x32_bf16(a1, b0[ch], acc[1][0], 0, 0, 0);
    acc[1][1] = __builtin_amdgcn_mfma_f32_16x16x32_bf16(a1, b1[ch], acc[1][1], 0, 0, 0);
  }
}

// ---------------- prep kernels ----------------

__global__ __launch_bounds__(256) void k_init(const void* __restrict__ f, float* __restrict__ ws) {
  const int bf = get_bf(ws);
  const int b = blockIdx.x;
  const int n = b >> 10, p = b & 1023;
  const int c = threadIdx.x;
  bf16* fb = (bf16*)(ws + OF_FEATB);
  fb[(size_t)b*CD + c] = f2bf(LD(f, ((size_t)n*CD + c)*PP + p, bf));
}

__global__ __launch_bounds__(256) void k_qh(const void* __restrict__ emb, const void* __restrict__ qw,
                                            const void* __restrict__ qb, const void* __restrict__ ipw,
                                            const void* __restrict__ ipb, float* __restrict__ ws) {
  const int bf = get_bf(ws);
  const int b = blockIdx.x, s = b / NB, n = b % NB;
  const int o = threadIdx.x;
  __shared__ float se[EMBD];
  __shared__ float sq[CD];
  for (int i = o; i < EMBD; i += CD) se[i] = LD(emb, ((size_t)n*SEQL + s)*EMBD + i, bf);
  __syncthreads();
  float a = LD(qb, o, bf);
  if (bf) {
    const bf16* wr = (const bf16*)qw + (size_t)o*EMBD;
    for (int c = 0; c < EMBD; ++c) a += se[c]*bf2f(wr[c]);
  } else {
    const float* wr = (const float*)qw + (size_t)o*EMBD;
    for (int c = 0; c < EMBD; ++c) a += se[c]*wr[c];
  }
  sq[o] = fmaxf(a, 0.f);
  __syncthreads();
  float a2 = LD(ipb, o, bf);
  if (bf) {
    const bf16* wq = (const bf16*)ipw + (size_t)o*CD;
    for (int c = 0; c < CD; ++c) a2 += sq[c]*bf2f(wq[c]);
  } else {
    const float* wq = (const float*)ipw + (size_t)o*CD;
    for (int c = 0; c < CD; ++c) a2 += sq[c]*wq[c];
  }
  ws[OF_QH + ((size_t)s*NB + n)*CD + o] = a2;
}

__global__ __launch_bounds__(256) void k_wregion(const void* __restrict__ mw, float* __restrict__ ws) {
  const int bf = get_bf(ws);
  const int gid = blockIdx.x*256 + threadIdx.x;
  const int c = gid & (HND-1);
  const int o = (gid >> 9) & (CD-1);
  const int r = gid >> 17;
  const int ry = r/3, rx = r%3;
  float s = 0.f;
  for (int dy = 0; dy < 3; ++dy) {
    if (ry == 0 && dy == 0) continue;
    if (ry == 2 && dy == 2) continue;
    for (int dx = 0; dx < 3; ++dx) {
      if (rx == 0 && dx == 0) continue;
      if (rx == 2 && dx == 2) continue;
      s += LD(mw, ((size_t)o*CIN + 264 + c)*9 + dy*3 + dx, bf);
    }
  }
  ws[OF_WRG + gid] = s;
}

__global__ __launch_bounds__(256) void k_hnw(const void* __restrict__ hn, float* __restrict__ ws) {
  const int bf = get_bf(ws);
  const int b = blockIdx.x, r = b / NB, n = b % NB;
  const int o = threadIdx.x;
  __shared__ float sh[HND];
  for (int i = o; i < HND; i += CD) sh[i] = LD(hn, (size_t)n*HND + i, bf);
  __syncthreads();
  const float* wr = ws + OF_WRG + ((size_t)r*CD + o)*HND;
  float a = 0.f;
  for (int c = 0; c < HND; ++c) a += sh[c]*wr[c];
  ws[OF_HNW + ((size_t)r*NB + n)*CD + o] = a;
}

DEV float spat(int c, int yy, int xx) {
  switch (c) {
    case 0: return xx*(1.f/16) - 1.f;
    case 1: return yy*(1.f/16) - 1.f;
    case 2: return (xx+1)*(1.f/16) - 1.f;
    case 3: return (yy+1)*(1.f/16) - 1.f;
    case 4: return (xx+0.5f)*(1.f/16) - 1.f;
    case 5: return (yy+0.5f)*(1.f/16) - 1.f;
    default: return 1.f/32;
  }
}

__global__ __launch_bounds__(256) void k_sconv(const void* __restrict__ mw, float* __restrict__ ws) {
  const int bf = get_bf(ws);
  const int p = blockIdx.x, o = threadIdx.x;
  const int y = p >> 5, x = p & 31;
  float a = 0.f;
  for (int c = 0; c < 8; ++c)
    for (int dy = 0; dy < 3; ++dy) {
      int yy = y + dy - 1; if ((unsigned)yy >= 32u) continue;
      for (int dx = 0; dx < 3; ++dx) {
        int xx = x + dx - 1; if ((unsigned)xx >= 32u) continue;
        a += LD(mw, ((size_t)o*CIN + 256 + c)*9 + dy*3 + dx, bf) * spat(c, yy, xx);
      }
    }
  ws[OF_SCV + (size_t)p*CD + o] = a;
}

// conv feat weights -> MFMA A-frag order: AW[it=tap*8+ch][mt][lane][8]
__global__ __launch_bounds__(256) void k_wpack(const void* __restrict__ mw, float* __restrict__ ws) {
  const int bf = get_bf(ws);
  const int idx = blockIdx.x*256 + threadIdx.x;
  const int j = idx & 7;
  const int lane = (idx >> 3) & 63;
  const int mt = (idx >> 9) & 15;
  const int ch = (idx >> 13) & 7;
  const int tap = idx >> 16;
  const int o = mt*16 + (lane & 15);
  const int c = ch*32 + (lane >> 4)*8 + j;
  bf16* aw = (bf16*)(ws + OF_AW);
  aw[idx] = f2bf(LD(mw, ((size_t)o*CIN + c)*9 + tap, bf));
}

// linear weights -> MFMA B-frag order: PK[g][nt][ch][lane][8]; g: 0=Wk 1=Wv 2=Wo 3=W1 4=W2
__global__ __launch_bounds__(256) void k_wpackB(const void* __restrict__ ipw, const void* __restrict__ opw,
                                                const void* __restrict__ l1w, const void* __restrict__ l2w,
                                                float* __restrict__ ws) {
  const int bf = get_bf(ws);
  const int idx = blockIdx.x*256 + threadIdx.x;
  const int j = idx & 7;
  const int lane = (idx >> 3) & 63;
  const int ch = (idx >> 9) & 7;
  const int nt = (idx >> 12) & 15;
  const int g = idx >> 16;
  const int o = nt*16 + (lane & 15);
  const int k = ch*32 + (lane >> 4)*8 + j;
  float v;
  switch (g) {
    case 0: v = LD(ipw, ((size_t)(256 + o))*CD + k, bf); break;
    case 1: v = LD(ipw, ((size_t)(512 + o))*CD + k, bf); break;
    case 2: v = LD(opw, (size_t)o*CD + k, bf);           break;
    case 3: v = LD(l1w, (size_t)o*CD + k, bf);           break;
    default: v = LD(l2w, (size_t)o*CD + k, bf);          break;
  }
  ((bf16*)(ws + OF_PK))[idx] = f2bf(v);
}

// ---------------- per-step kernels ----------------

// FUSED conv+LN+KV [R13]: 256 blocks x 1024 thr, block=(n, yp: rows 2yp, 2yp+1).
// 16 waves; wave w owns o-tile w for BOTH rows: each A-frag feeds 4 MFMAs
// (2 rows x 2 x-halves) -> A-weight L1/L2 traffic HALVED (2.3->1.15 MB/CU)
// while keeping 4 waves/SIMD (R5's 512-thr 2-row variant dropped to 2/SIMD and lost).
__global__ __launch_bounds__(1024, 4) void k_convkv(const void* __restrict__ mg, const void* __restrict__ mbv,
                                                    const void* __restrict__ ipb, float* __restrict__ ws) {
  __shared__ float smem[17952];            // 71,808 B: Xs[4][34][264] shorts
  short* Xs = (short*)smem;
  float* red  = smem;                      // aliases Xs after conv: partials[1024] sq[1024] stats[128]
  short* AsT  = (short*)(smem + 2176);     // t staging [64][264] shorts (8448 f) -> ends 10624 < 17952
  const int bfv = get_bf(ws);
  const int b = blockIdx.x, n = b >> 4, yp = b & 15;
  const int y0 = yp*2;
  const int tid = threadIdx.x;
  const int w = tid >> 6, lane = tid & 63;      // 16 waves
  const int xb = lane & 15, quad = lane >> 4;
  const bf16* fb = (const bf16*)(ws + OF_FEATB);

  // ---- stage input rows y0-1..y0+2 zero-padded, transposed: Xs[r][1+x][c] ----
  const short8 zero8 = {0,0,0,0,0,0,0,0};
  if (tid < 256) {
    const int r = tid >> 6, xp = ((tid >> 5) & 1) * 33, c0 = (tid & 31)*8;
    *(short8*)&Xs[(r*34 + xp)*264 + c0] = zero8;
  }
#pragma unroll
  for (int u = 0; u < 4; ++u) {
    const int lin = u*1024 + tid;
    const int cgrp = lin & 31, xl = (lin >> 5) & 31, r = lin >> 10;
    const int row = y0 + r - 1;
    short8 v = zero8;
    if ((unsigned)row < 32u)
      v = *(const short8*)&fb[((size_t)(n*PP + row*32 + xl))*CD + cgrp*8];
    *(short8*)&Xs[(r*34 + 1 + xl)*264 + cgrp*8] = v;
  }
  __syncthreads();

  // ---- conv MFMA K-loop: wave w owns o-tile w; 1 A-frag -> 4 MFMAs ----
  float4v acc[2][2];   // [rr][xhalf]
#pragma unroll
  for (int rr = 0; rr < 2; ++rr) { acc[rr][0] = (float4v)0.f; acc[rr][1] = (float4v)0.f; }
  const bf16* AW = (const bf16*)(ws + OF_AW);
  const int bvec = xb*264 + quad*8;   // vector part of B address

  short8 A0[3], B00[3], B01[3], B10[3], B11[3];
#define PF(GI, S) do {                                                        \
    const int tap_ = (GI) >> 3, ch_ = (GI) & 7;                               \
    const int dy_ = (tap_ >= 6) ? 2 : ((tap_ >= 3) ? 1 : 0);                  \
    const int dx_ = tap_ - 3*dy_;                                             \
    const bf16* ap_ = AW + (((size_t)(tap_*8 + ch_)*16 + w)*64 + lane)*8;     \
    A0[S] = *(const short8*)&ap_[0];                                          \
    const short* bp0_ = &Xs[(dy_*34 + dx_)*264 + ch_*32 + bvec];              \
    B00[S] = *(const short8*)&bp0_[0];                                        \
    B01[S] = *(const short8*)&bp0_[16*264];                                   \
    const short* bp1_ = bp0_ + 34*264;                                        \
    B10[S] = *(const short8*)&bp1_[0];                                        \
    B11[S] = *(const short8*)&bp1_[16*264];                                   \
  } while (0)

  PF(0, 0); PF(1, 1); PF(2, 2);
#pragma unroll
  for (int gi = 0; gi < 72; ++gi) {
    const int s = gi % 3;
    acc[0][0] = __builtin_amdgcn_mfma_f32_16x16x32_bf16(A0[s], B00[s], acc[0][0], 0, 0, 0);
    acc[0][1] = __builtin_amdgcn_mfma_f32_16x16x32_bf16(A0[s], B01[s], acc[0][1], 0, 0, 0);
    acc[1][0] = __builtin_amdgcn_mfma_f32_16x16x32_bf16(A0[s], B10[s], acc[1][0], 0, 0, 0);
    acc[1][1] = __builtin_amdgcn_mfma_f32_16x16x32_bf16(A0[s], B11[s], acc[1][1], 0, 0, 0);
    if (gi < 69) PF(gi + 3, s);
  }
#undef PF
  __syncthreads();   // Xs dead; red/AsT region safe to write

  // ---- in-register epilogue: lane holds D[o = w*16+quad*4+r][x = xh*16+xb] per row rr
  const int ob = w*16 + quad*4;   // channel base (4 channels)
  float vv[2][2][4];              // [rr][xh][r]
  float g4[4], b4[4];
#pragma unroll
  for (int r = 0; r < 4; ++r) { g4[r] = LD(mg, ob + r, bfv); b4[r] = LD(mbv, ob + r, bfv); }
#pragma unroll
  for (int rr = 0; rr < 2; ++rr) {
    const int yr = y0 + rr;
    const int ry = (yr == 0) ? 0 : ((yr == 31) ? 2 : 1);
    const float* hnw = ws + OF_HNW;
    float4 hL = *(const float4*)&hnw[((size_t)(ry*3+0)*NB + n)*CD + ob];
    float4 hM = *(const float4*)&hnw[((size_t)(ry*3+1)*NB + n)*CD + ob];
    float4 hR = *(const float4*)&hnw[((size_t)(ry*3+2)*NB + n)*CD + ob];
    const float* scv = ws + OF_SCV + (size_t)(yr*32)*CD;
#pragma unroll
    for (int xh = 0; xh < 2; ++xh) {
      const int x = xh*16 + xb;
      float4 sc = *(const float4*)&scv[(size_t)x*CD + ob];
      float4 hh = (x == 0) ? hL : ((x == 31) ? hR : hM);
      const float* scp = (const float*)&sc;
      const float* hhp = (const float*)&hh;
#pragma unroll
      for (int r = 0; r < 4; ++r)
        vv[rr][xh][r] = fmaxf(acc[rr][xh][r] + scp[r] + hhp[r], 0.f);
    }
  }
  // per-(rr,x) partial sums over this lane's 4 channels; butterfly over quads
#pragma unroll
  for (int rr = 0; rr < 2; ++rr)
#pragma unroll
    for (int xh = 0; xh < 2; ++xh) {
      float s = 0.f, q = 0.f;
#pragma unroll
      for (int r = 0; r < 4; ++r) { s += vv[rr][xh][r]; q += vv[rr][xh][r]*vv[rr][xh][r]; }
      s += __shfl_xor(s, 16, 64); s += __shfl_xor(s, 32, 64);
      q += __shfl_xor(q, 16, 64); q += __shfl_xor(q, 32, 64);
      if (quad == 0) {
        red[(rr*32 + xh*16 + xb)*16 + w] = s;
        red[1024 + (rr*32 + xh*16 + xb)*16 + w] = q;
      }
    }
  __syncthreads();
  if (tid < 64) {
    float ts = 0.f, tq = 0.f;
#pragma unroll
    for (int g = 0; g < 16; ++g) { ts += red[tid*16 + g]; tq += red[1024 + tid*16 + g]; }
    float m = ts * (1.f/CD);
    float var = tq * (1.f/CD) - m*m;
    red[2048 + tid] = m;
    red[2112 + tid] = 1.f / sqrtf(var + 1e-5f);
  }
  __syncthreads();
#pragma unroll
  for (int rr = 0; rr < 2; ++rr)
#pragma unroll
    for (int xh = 0; xh < 2; ++xh) {
      const int px = rr*32 + xh*16 + xb;   // local pixel row in AsT
      const float m = red[2048 + px], rs = red[2112 + px];
      short4v t;
#pragma unroll
      for (int r = 0; r < 4; ++r) t[r] = f2sh((vv[rr][xh][r] - m)*rs*g4[r] + b4[r]);
      *(short4v*)&AsT[px*264 + ob] = t;
    }
  __syncthreads();   // AsT ready (64 local pixel rows)

  // ---- coalesced TB stream from AsT ----
  {
    bf16* tp = (bf16*)(ws + OF_TB) + ((size_t)n*PP + (size_t)y0*32)*CD;
    const int r = tid >> 4, c0 = (tid & 15)*16;
#pragma unroll
    for (int i = 0; i < 2; ++i) {
      short8 v = *(const short8*)&AsT[r*264 + c0 + i*8];
      *(short8*)&tp[(size_t)r*CD + c0 + i*8] = v;
    }
  }

  // ---- K and V projections: wave w owns c-tile w; 2 row-groups of 32 ----
  const short* PK = (const short*)(ws + OF_PK);
  const int p0 = y0 << 5;
#pragma unroll 1
  for (int G = 0; G < 2; ++G) {
    const short* PKg = PK + (size_t)G*65536;
    const short* base = PKg + lane*8;
    short8 bfr[8];
#pragma unroll
    for (int ch = 0; ch < 8; ++ch)
      bfr[ch] = *(const short8*)&base[(size_t)(w*8 + ch)*512];
    bf16* dst = (bf16*)(ws + (G ? OF_VVB : OF_KHB)) + ((size_t)n*PP + p0)*CD;
    const int c = w*16 + xb;
    const float bias = LD(ipb, (size_t)(G+1)*256 + c, bfv);
#pragma unroll 1
    for (int rg = 0; rg < 2; ++rg) {
      float4v ac2[2];
      ac2[0] = (float4v)0.f; ac2[1] = (float4v)0.f;
#pragma unroll
      for (int ch = 0; ch < 8; ++ch) {
        short8 a0 = *(const short8*)&AsT[(rg*32 + xb)*264 + ch*32 + quad*8];
        short8 a1 = *(const short8*)&AsT[(rg*32 + 16 + xb)*264 + ch*32 + quad*8];
        ac2[0] = __builtin_amdgcn_mfma_f32_16x16x32_bf16(a0, bfr[ch], ac2[0], 0, 0, 0);
        ac2[1] = __builtin_amdgcn_mfma_f32_16x16x32_bf16(a1, bfr[ch], ac2[1], 0, 0, 0);
      }
#pragma unroll
      for (int mt = 0; mt < 2; ++mt)
#pragma unroll
        for (int r = 0; r < 4; ++r)
          dst[(size_t)(rg*32 + mt*16 + quad*4 + r)*CD + c] = f2bf(ac2[mt][r] + bias);
    }
  }
}

// FUSED attn+outproj+LN+lin1+lin2+LN+commit: 512 blocks x 512 thr. [R12 form, unchanged]
__global__ __launch_bounds__(512, 4) void k_oplin(const void* __restrict__ opb, const void* __restrict__ ng,
                                                  const void* __restrict__ nbv, const void* __restrict__ l1b,
                                                  const void* __restrict__ l2b, const void* __restrict__ nfg,
                                                  const void* __restrict__ nfb, const int* __restrict__ words,
                                                  int s, float* __restrict__ ws) {
  __shared__ float smem[15040];            // 60,160 B
  float* tile = smem;                      // [256][33] fp32 (aliases AsT/SQb)
  float* red  = smem + 8448;               // 1088 f
  short* AsT  = (short*)smem;              // [32][264] bf16 A-tile
  short* AsF  = (short*)(smem + 9536);     // [32][264] bf16 fea (aliases SVs)
  short* SQb  = (short*)smem;              // attn: [16][264] bf16 q rows (dead before AsT writes)
  short* SKs  = (short*)(smem + 4224);     // attn: [2][16][264] bf16 K rows
  short* SVs  = (short*)(smem + 9536);     // attn: [2][16][264] bf16 V rows
  short* Pb   = (short*)(smem + 13760);    // attn: [4][16][18] bf16 probs
  const int bf = get_bf(ws);
  const int b = blockIdx.x, p0 = b*2;
  const int tid = threadIdx.x, w = tid >> 6, lane = tid & 63;
  const int xb = lane & 15, quad = lane >> 4;
  const int o = tid & 255, half = tid >> 8;
  const short* PK = (const short*)(ws + OF_PK);
  const int c0i = (w*2 + 0)*16 + xb;
  const int c1i = (w*2 + 1)*16 + xb;

  // ---- stage SQ (bf16) + SK/SV (bf16) for both pixels ----
  {
    const int l = tid >> 5, c0 = (tid & 31)*8;
    const float* src = ws + OF_QH + ((size_t)(s*NB + l))*CD + c0;
    float4 q0 = *(const float4*)&src[0];
    float4 q1 = *(const float4*)&src[4];
    short8 t;
    t[0] = f2sh(q0.x); t[1] = f2sh(q0.y); t[2] = f2sh(q0.z); t[3] = f2sh(q0.w);
    t[4] = f2sh(q1.x); t[5] = f2sh(q1.y); t[6] = f2sh(q1.z); t[7] = f2sh(q1.w);
    *(short8*)&SQb[l*264 + c0] = t;
  }
  {
    const int row = tid >> 4, c0 = (tid & 15)*16;   // row = pp*16 + l
    const int pp = row >> 4, l = row & 15;
    const size_t srcoff = ((size_t)l*PP + (p0 + pp))*CD + c0;
    const bf16* khb = (const bf16*)(ws + OF_KHB);
    const bf16* vvb = (const bf16*)(ws + OF_VVB);
    *(short8*)&SKs[row*264 + c0]     = *(const short8*)&khb[srcoff];
    *(short8*)&SKs[row*264 + c0 + 8] = *(const short8*)&khb[srcoff + 8];
    *(short8*)&SVs[row*264 + c0]     = *(const short8*)&vvb[srcoff];
    *(short8*)&SVs[row*264 + c0 + 8] = *(const short8*)&vvb[srcoff + 8];
  }
  __syncthreads();

  // ---- QK^T + softmax: waves 0-3, one unit (pp=aq, head=hq) each ----
  if (w < 4) {
    const int aq = w >> 1, hq = w & 1;
    float4v sacc = (float4v)0.f;
#pragma unroll
    for (int ch = 0; ch < 4; ++ch) {
      short8 qa = *(const short8*)&SQb[xb*264 + hq*128 + ch*32 + quad*8];
      short8 kb = *(const short8*)&SKs[(aq*16 + xb)*264 + hq*128 + ch*32 + quad*8];
      sacc = __builtin_amdgcn_mfma_f32_16x16x32_bf16(qa, kb, sacc, 0, 0, 0);
    }
#pragma unroll
    for (int r = 0; r < 4; ++r) {
      float sc = sacc[r] * 0.08838834764831845f;
      float mx = sc;
      mx = fmaxf(mx, __shfl_xor(mx, 1, 64));
      mx = fmaxf(mx, __shfl_xor(mx, 2, 64));
      mx = fmaxf(mx, __shfl_xor(mx, 4, 64));
      mx = fmaxf(mx, __shfl_xor(mx, 8, 64));
      float e = __expf(sc - mx);
      float su = e;
      su += __shfl_xor(su, 1, 64);
      su += __shfl_xor(su, 2, 64);
      su += __shfl_xor(su, 4, 64);
      su += __shfl_xor(su, 8, 64);
      Pb[(w*16 + quad*4 + r)*18 + xb] = f2sh(e / su);
    }
  }
  __syncthreads();   // Pb ready; SQb dead

  // ---- PV: all 8 waves; wave = (unit u=w>>1, d-half dh=w&1); ao -> AsT ----
  {
    const int u = w >> 1, ap = u >> 1, hp = u & 1, dh = w & 1;
    short8 pa = {0,0,0,0,0,0,0,0};
    if (quad < 2) pa = *(const short8*)&Pb[(u*16 + xb)*18 + quad*8];
#pragma unroll
    for (int t = 0; t < 4; ++t) {
      const int dcol = hp*128 + dh*64 + t*16 + xb;
      short8 vb;
#pragma unroll
      for (int j = 0; j < 8; ++j)
        vb[j] = SVs[(ap*16 + (quad & 1)*8 + j)*264 + dcol];   // in-bounds; quad>=2 killed by zero A
      float4v acc = (float4v)0.f;
      acc = __builtin_amdgcn_mfma_f32_16x16x32_bf16(pa, vb, acc, 0, 0, 0);
#pragma unroll
      for (int r = 0; r < 4; ++r)
        AsT[(ap*16 + quad*4 + r)*264 + dcol] = f2sh(acc[r]);
    }
  }
  __syncthreads();   // AsT ready

  // ---- outproj: MFMA + residual folded in regs -> tile -> LN ----
  float vo[2][2][4];
  {
    float4v acc[2][2];
#pragma unroll
    for (int mt = 0; mt < 2; ++mt) { acc[mt][0] = (float4v)0.f; acc[mt][1] = (float4v)0.f; }
    mfma_core512(AsT, PK + (size_t)2*65536, w, lane, acc);
    const float bo0 = LD(opb, c0i, bf), bo1 = LD(opb, c1i, bf);
    const bf16* tb = (const bf16*)(ws + OF_TB);
#pragma unroll
    for (int mt = 0; mt < 2; ++mt)
#pragma unroll
      for (int r = 0; r < 4; ++r) {
        const int x = mt*16 + quad*4 + r;
        const size_t prow = ((size_t)(x & 15)*PP + p0 + (x >> 4))*CD;
        vo[mt][0][r] = acc[mt][0][r] + bo0 + bf2f(tb[prow + c0i]);
        vo[mt][1][r] = acc[mt][1][r] + bo1 + bf2f(tb[prow + c1i]);
      }
  }
  __syncthreads();   // AsT reads done before tile overwrite
#pragma unroll
  for (int i = 0; i < 2; ++i)
#pragma unroll
    for (int mt = 0; mt < 2; ++mt)
#pragma unroll
      for (int r = 0; r < 4; ++r)
        tile[((w*2 + i)*16 + xb)*33 + mt*16 + quad*4 + r] = vo[mt][i][r];
  __syncthreads();
  ln_reduce512(tile, red, tid);
  {
    const float g = LD(ng, o, bf), bb = LD(nbv, o, bf);
#pragma unroll
    for (int xi = 0; xi < 16; ++xi) {
      const int x = half*16 + xi;
      AsF[x*264 + o] = f2sh((tile[o*33 + x] - red[1024 + x]) * red[1056 + x] * g + bb);
    }
  }
  __syncthreads();   // AsF ready; tile dead

  // ---- lin1: fea -> relu -> AsT ----
  {
    float4v acc[2][2];
#pragma unroll
    for (int mt = 0; mt < 2; ++mt) { acc[mt][0] = (float4v)0.f; acc[mt][1] = (float4v)0.f; }
    mfma_core512(AsF, PK + (size_t)3*65536, w, lane, acc);
#pragma unroll
    for (int i = 0; i < 2; ++i) {
      const int c = (w*2 + i)*16 + xb;
      const float bias = LD(l1b, c, bf);
#pragma unroll
      for (int mt = 0; mt < 2; ++mt)
#pragma unroll
        for (int r = 0; r < 4; ++r)
          AsT[(mt*16 + quad*4 + r)*264 + c] = f2sh(fmaxf(acc[mt][i][r] + bias, 0.f));
    }
  }
  __syncthreads();

  // ---- lin2: MFMA + residual (AsF) folded in regs -> tile -> LN + commit ----
  {
    float4v acc[2][2];
#pragma unroll
    for (int mt = 0; mt < 2; ++mt) { acc[mt][0] = (float4v)0.f; acc[mt][1] = (float4v)0.f; }
    mfma_core512(AsT, PK + (size_t)4*65536, w, lane, acc);
    const float bl0 = LD(l2b, c0i, bf), bl1 = LD(l2b, c1i, bf);
#pragma unroll
    for (int mt = 0; mt < 2; ++mt)
#pragma unroll
      for (int r = 0; r < 4; ++r) {
        const int x = mt*16 + quad*4 + r;
        vo[mt][0][r] = acc[mt][0][r] + bl0 + sh2f(AsF[x*264 + c0i]);
        vo[mt][1][r] = acc[mt][1][r] + bl1 + sh2f(AsF[x*264 + c1i]);
      }
  }
  __syncthreads();   // AsT reads done before tile overwrite
#pragma unroll
  for (int i = 0; i < 2; ++i)
#pragma unroll
    for (int mt = 0; mt < 2; ++mt)
#pragma unroll
      for (int r = 0; r < 4; ++r)
        tile[((w*2 + i)*16 + xb)*33 + mt*16 + quad*4 + r] = vo[mt][i][r];
  __syncthreads();
  ln_reduce512(tile, red, tid);
  if (words[s] != 0) {
    const float g = LD(nfg, o, bf), b2 = LD(nfb, o, bf);
    bf16* fbd = (bf16*)(ws + OF_FEATB);
#pragma unroll
    for (int xi = 0; xi < 16; ++xi) {
      const int x = half*16 + xi;
      fbd[((size_t)(x & 15)*PP + p0 + (x >> 4))*CD + o] =
          f2bf((tile[o*33 + x] - red[1024 + x]) * red[1056 + x] * g + b2);
    }
  }
}

// output [n][c][p] from bf16 feat [n][p][c]
__global__ __launch_bounds__(256) void k_final(const float* __restrict__ ws, void* __restrict__ out) {
  const int bf = get_bf(ws);
  const size_t i = (size_t)blockIdx.x*256 + threadIdx.x;
  const int n = (int)(i >> 18), c = (int)((i >> 10) & 255), p = (int)(i & 1023);
  const bf16* fb = (const bf16*)(ws + OF_FEATB);
  float v = bf2f(fb[((size_t)(n*PP + p))*CD + c]);
  if (bf) ((bf16*)out)[i] = f2bf(v);
  else    ((float*)out)[i] = v;
}

extern "C" void kernel_launch(void* const* d_in, const int* in_sizes, int n_in,
                              void* d_out, int out_size, void* d_ws, size_t ws_size,
                              hipStream_t stream) {
  (void)in_sizes; (void)n_in; (void)out_size; (void)ws_size;
  const void* hn      = d_in[1];
  const void* feature = d_in[2];
  const void* emb     = d_in[3];
  const int*  words   = (const int*)d_in[4];
  const void* qw  = d_in[5];
  const void* qb  = d_in[6];
  const void* mw  = d_in[7];
  const void* mg  = d_in[8];
  const void* mb  = d_in[9];
  const void* ipw = d_in[10];
  const void* ipb = d_in[11];
  const void* opw = d_in[12];
  const void* opb = d_in[13];
  const void* ng  = d_in[14];
  const void* nb  = d_in[15];
  const void* l1w = d_in[16];
  const void* l1b = d_in[17];
  const void* l2w = d_in[18];
  const void* l2b = d_in[19];
  const void* nfg = d_in[20];
  const void* nfb = d_in[21];
  float* ws = (float*)d_ws;

  k_detect<<<1, 64, 0, stream>>>(mg, ws);
  k_init<<<NB*PP, 256, 0, stream>>>(feature, ws);
  k_qh<<<SEQL*NB, 256, 0, stream>>>(emb, qw, qb, ipw, ipb, ws);
  k_wregion<<<(9*CD*HND)/256, 256, 0, stream>>>(mw, ws);
  k_hnw<<<9*NB, 256, 0, stream>>>(hn, ws);
  k_sconv<<<PP, 256, 0, stream>>>(mw, ws);
  k_wpack<<<(9*8*16*64*8)/256, 256, 0, stream>>>(mw, ws);
  k_wpackB<<<(5*65536)/256, 256, 0, stream>>>(ipw, opw, l1w, l2w, ws);

  for (int s = 0; s < SEQL; ++s) {
    k_convkv<<<NB*16, 1024, 0, stream>>>(mg, mb, ipb, ws);
    k_oplin<<<PP/2, 512, 0, stream>>>(opb, ng, nb, l1b, l2b, nfg, nfb, words, s, ws);
  }
  k_final<<<NB*CD*PP/256, 256, 0, stream>>>(ws, (void*)d_out);
}

// Round 14
// 1381.270 us; speedup vs baseline: 1.6084x; 1.6084x over previous
//
#include <hip/hip_runtime.h>
#include <hip/hip_bf16.h>
#include <cstddef>

typedef __hip_bfloat16 bf16;
typedef short short8 __attribute__((ext_vector_type(8)));
typedef short short4v __attribute__((ext_vector_type(4)));
typedef float float4v __attribute__((ext_vector_type(4)));
#define DEV static __device__ __forceinline__

constexpr int NB = 16;     // batch
constexpr int SEQL = 20;
constexpr int CD = 256;    // VD
constexpr int PP = 1024;   // 32*32
constexpr int HND = 512;
constexpr int EMBD = 300;
constexpr int CIN = 776;   // 256 + 8 + 512

// ---- workspace layout (float element offsets); bf16 buffers are [n][p][c] ----
constexpr size_t SZB = (size_t)NB * PP * CD / 2;             // floats per bf16 NPC buffer
constexpr size_t OF_FEATB = 0;                               // running feature (bf16)
constexpr size_t OF_TB   = 1*SZB;                            // t (bf16)
constexpr size_t OF_KHB  = 2*SZB;                            // kh (bf16)
constexpr size_t OF_VVB  = 3*SZB;                            // vv (bf16)
constexpr size_t OF_QH   = 7*SZB;                            // qh [s][n][c] fp32
constexpr size_t OF_HNW  = OF_QH  + (size_t)SEQL*NB*CD;      // hnW [r][n][o] fp32
constexpr size_t OF_SCV  = OF_HNW + (size_t)9*NB*CD;         // sconv [p][o] fp32
constexpr size_t OF_WRG  = OF_SCV + (size_t)PP*CD;           // W_region [r][o][c] fp32
constexpr size_t OF_AW   = OF_WRG + (size_t)9*CD*HND;        // conv W A-frags (589,824 bf16)
constexpr size_t OF_PK   = OF_AW  + (size_t)294912;          // linear W B-frags: 5 x 65,536 bf16
constexpr size_t OF_FLAG = OF_PK  + (size_t)163840;          // dtype flag

DEV float bf2f(bf16 v) { return __bfloat162float(v); }
DEV bf16 f2bf(float v) { return __float2bfloat16(v); }
DEV float sh2f(short v) { bf16 t; *(short*)&t = v; return __bfloat162float(t); }
DEV short f2sh(float v) { bf16 t = f2bf(v); return *(const short*)&t; }

DEV float LD(const void* p, size_t i, int bf) {
  return bf ? __bfloat162float(((const bf16*)p)[i]) : ((const float*)p)[i];
}
DEV int get_bf(const float* ws) { return ((const int*)ws)[OF_FLAG]; }

__global__ void k_detect(const void* g, float* ws) {
  if (threadIdx.x == 0 && blockIdx.x == 0) {
    unsigned w = *(const unsigned*)g;
    ((int*)ws)[OF_FLAG] = ((w & 0xFFFFu) != 0u) ? 1 : 0;
  }
}

// LN reduction, 512 threads: tile[o][x] stride 33; red[1024+x]=mean, red[1056+x]=rstd
// NOTE (R9 lesson): do NOT replace with __shfl chains — shfl = ds_swizzle (LDS pipe).
DEV void ln_reduce512(const float* tile, float* red, int tid) {
  const int x = tid & 31, seg = tid >> 5;   // 16 segs of 16 channels
  float s = 0.f, sq = 0.f;
#pragma unroll
  for (int i = 0; i < 16; ++i) {
    float v = tile[(seg*16 + i)*33 + x];
    s += v; sq += v*v;
  }
  red[seg*32 + x] = s;
  red[512 + seg*32 + x] = sq;
  __syncthreads();
  if (tid < 32) {
    float ts = 0.f, tq = 0.f;
#pragma unroll
    for (int g = 0; g < 16; ++g) { ts += red[g*32 + tid]; tq += red[512 + g*32 + tid]; }
    float m = ts * (1.f/CD);
    float var = tq * (1.f/CD) - m*m;
    red[1024 + tid] = m;
    red[1056 + tid] = 1.f / sqrtf(var + 1e-5f);
  }
  __syncthreads();
}

// 512-thr linear core: ALL 16 global B-frags preloaded up front.
// Layout (production-validated): A m=lane&15, k=(lane>>4)*8+j; B n=lane&15, same k;
// D m=(lane>>4)*4+r, n=lane&15.
DEV void mfma_core512(const short* __restrict__ As, const short* __restrict__ PKg,
                      int w, int lane, float4v acc[2][2]) {
  const int xb = lane & 15, quad = lane >> 4;
  const short* base = PKg + lane*8;
  short8 b0[8], b1[8];
#pragma unroll
  for (int ch = 0; ch < 8; ++ch) {
    b0[ch] = *(const short8*)&base[(size_t)((w*2+0)*8 + ch)*512];
    b1[ch] = *(const short8*)&base[(size_t)((w*2+1)*8 + ch)*512];
  }
#pragma unroll
  for (int ch = 0; ch < 8; ++ch) {
    short8 a0 = *(const short8*)&As[xb*264 + ch*32 + quad*8];
    short8 a1 = *(const short8*)&As[(16+xb)*264 + ch*32 + quad*8];
    acc[0][0] = __builtin_amdgcn_mfma_f32_16x16x32_bf16(a0, b0[ch], acc[0][0], 0, 0, 0);
    acc[0][1] = __builtin_amdgcn_mfma_f32_16x16x32_bf16(a0, b1[ch], acc[0][1], 0, 0, 0);
    acc[1][0] = __builtin_amdgcn_mfma_f32_16x16x32_bf16(a1, b0[ch], acc[1][0], 0, 0, 0);
    acc[1][1] = __builtin_amdgcn_mfma_f32_16x16x32_bf16(a1, b1[ch], acc[1][1], 0, 0, 0);
  }
}

// ---------------- prep kernels ----------------

__global__ __launch_bounds__(256) void k_init(const void* __restrict__ f, float* __restrict__ ws) {
  const int bf = get_bf(ws);
  const int b = blockIdx.x;
  const int n = b >> 10, p = b & 1023;
  const int c = threadIdx.x;
  bf16* fb = (bf16*)(ws + OF_FEATB);
  fb[(size_t)b*CD + c] = f2bf(LD(f, ((size_t)n*CD + c)*PP + p, bf));
}

__global__ __launch_bounds__(256) void k_qh(const void* __restrict__ emb, const void* __restrict__ qw,
                                            const void* __restrict__ qb, const void* __restrict__ ipw,
                                            const void* __restrict__ ipb, float* __restrict__ ws) {
  const int bf = get_bf(ws);
  const int b = blockIdx.x, s = b / NB, n = b % NB;
  const int o = threadIdx.x;
  __shared__ float se[EMBD];
  __shared__ float sq[CD];
  for (int i = o; i < EMBD; i += CD) se[i] = LD(emb, ((size_t)n*SEQL + s)*EMBD + i, bf);
  __syncthreads();
  float a = LD(qb, o, bf);
  if (bf) {
    const bf16* wr = (const bf16*)qw + (size_t)o*EMBD;
    for (int c = 0; c < EMBD; ++c) a += se[c]*bf2f(wr[c]);
  } else {
    const float* wr = (const float*)qw + (size_t)o*EMBD;
    for (int c = 0; c < EMBD; ++c) a += se[c]*wr[c];
  }
  sq[o] = fmaxf(a, 0.f);
  __syncthreads();
  float a2 = LD(ipb, o, bf);
  if (bf) {
    const bf16* wq = (const bf16*)ipw + (size_t)o*CD;
    for (int c = 0; c < CD; ++c) a2 += sq[c]*bf2f(wq[c]);
  } else {
    const float* wq = (const float*)ipw + (size_t)o*CD;
    for (int c = 0; c < CD; ++c) a2 += sq[c]*wq[c];
  }
  ws[OF_QH + ((size_t)s*NB + n)*CD + o] = a2;
}

__global__ __launch_bounds__(256) void k_wregion(const void* __restrict__ mw, float* __restrict__ ws) {
  const int bf = get_bf(ws);
  const int gid = blockIdx.x*256 + threadIdx.x;
  const int c = gid & (HND-1);
  const int o = (gid >> 9) & (CD-1);
  const int r = gid >> 17;
  const int ry = r/3, rx = r%3;
  float s = 0.f;
  for (int dy = 0; dy < 3; ++dy) {
    if (ry == 0 && dy == 0) continue;
    if (ry == 2 && dy == 2) continue;
    for (int dx = 0; dx < 3; ++dx) {
      if (rx == 0 && dx == 0) continue;
      if (rx == 2 && dx == 2) continue;
      s += LD(mw, ((size_t)o*CIN + 264 + c)*9 + dy*3 + dx, bf);
    }
  }
  ws[OF_WRG + gid] = s;
}

__global__ __launch_bounds__(256) void k_hnw(const void* __restrict__ hn, float* __restrict__ ws) {
  const int bf = get_bf(ws);
  const int b = blockIdx.x, r = b / NB, n = b % NB;
  const int o = threadIdx.x;
  __shared__ float sh[HND];
  for (int i = o; i < HND; i += CD) sh[i] = LD(hn, (size_t)n*HND + i, bf);
  __syncthreads();
  const float* wr = ws + OF_WRG + ((size_t)r*CD + o)*HND;
  float a = 0.f;
  for (int c = 0; c < HND; ++c) a += sh[c]*wr[c];
  ws[OF_HNW + ((size_t)r*NB + n)*CD + o] = a;
}

DEV float spat(int c, int yy, int xx) {
  switch (c) {
    case 0: return xx*(1.f/16) - 1.f;
    case 1: return yy*(1.f/16) - 1.f;
    case 2: return (xx+1)*(1.f/16) - 1.f;
    case 3: return (yy+1)*(1.f/16) - 1.f;
    case 4: return (xx+0.5f)*(1.f/16) - 1.f;
    case 5: return (yy+0.5f)*(1.f/16) - 1.f;
    default: return 1.f/32;
  }
}

__global__ __launch_bounds__(256) void k_sconv(const void* __restrict__ mw, float* __restrict__ ws) {
  const int bf = get_bf(ws);
  const int p = blockIdx.x, o = threadIdx.x;
  const int y = p >> 5, x = p & 31;
  float a = 0.f;
  for (int c = 0; c < 8; ++c)
    for (int dy = 0; dy < 3; ++dy) {
      int yy = y + dy - 1; if ((unsigned)yy >= 32u) continue;
      for (int dx = 0; dx < 3; ++dx) {
        int xx = x + dx - 1; if ((unsigned)xx >= 32u) continue;
        a += LD(mw, ((size_t)o*CIN + 256 + c)*9 + dy*3 + dx, bf) * spat(c, yy, xx);
      }
    }
  ws[OF_SCV + (size_t)p*CD + o] = a;
}

// conv feat weights -> MFMA A-frag order: AW[it=tap*8+ch][mt][lane][8]
__global__ __launch_bounds__(256) void k_wpack(const void* __restrict__ mw, float* __restrict__ ws) {
  const int bf = get_bf(ws);
  const int idx = blockIdx.x*256 + threadIdx.x;
  const int j = idx & 7;
  const int lane = (idx >> 3) & 63;
  const int mt = (idx >> 9) & 15;
  const int ch = (idx >> 13) & 7;
  const int tap = idx >> 16;
  const int o = mt*16 + (lane & 15);
  const int c = ch*32 + (lane >> 4)*8 + j;
  bf16* aw = (bf16*)(ws + OF_AW);
  aw[idx] = f2bf(LD(mw, ((size_t)o*CIN + c)*9 + tap, bf));
}

// linear weights -> MFMA B-frag order: PK[g][nt][ch][lane][8]; g: 0=Wk 1=Wv 2=Wo 3=W1 4=W2
__global__ __launch_bounds__(256) void k_wpackB(const void* __restrict__ ipw, const void* __restrict__ opw,
                                                const void* __restrict__ l1w, const void* __restrict__ l2w,
                                                float* __restrict__ ws) {
  const int bf = get_bf(ws);
  const int idx = blockIdx.x*256 + threadIdx.x;
  const int j = idx & 7;
  const int lane = (idx >> 3) & 63;
  const int ch = (idx >> 9) & 7;
  const int nt = (idx >> 12) & 15;
  const int g = idx >> 16;
  const int o = nt*16 + (lane & 15);
  const int k = ch*32 + (lane >> 4)*8 + j;
  float v;
  switch (g) {
    case 0: v = LD(ipw, ((size_t)(256 + o))*CD + k, bf); break;
    case 1: v = LD(ipw, ((size_t)(512 + o))*CD + k, bf); break;
    case 2: v = LD(opw, (size_t)o*CD + k, bf);           break;
    case 3: v = LD(l1w, (size_t)o*CD + k, bf);           break;
    default: v = LD(l2w, (size_t)o*CD + k, bf);          break;
  }
  ((bf16*)(ws + OF_PK))[idx] = f2bf(v);
}

// ---------------- per-step kernels ----------------

// FUSED conv+LN+KV: 512 blocks x 512 thr, block=(n,y). [R12 form — best measured 43.0us]
// NOTE (R5/R13 lessons): 2-row reuse variants fail — 512thr/2-row drops to 2 waves/SIMD
// (R5, latency-bound); 1024thr/2-row caps VGPR via 4-waves/SIMD residency and spills
// massively (R13: WRITE_SIZE 24.6->223MB). This 512thr/1-row shape is register-feasible.
__global__ __launch_bounds__(512, 4) void k_convkv(const void* __restrict__ mg, const void* __restrict__ mbv,
                                                   const void* __restrict__ ipb, float* __restrict__ ws) {
  __shared__ float smem[13464];            // 53,856 B
  short* Xs = (short*)smem;                // conv input stage (dead after conv)
  float* red  = smem;                      // aliases Xs: [0..255] sums, [256..511] sqsums, [512..575] stats
  short* AsT  = (short*)(smem + 576);      // t staging for K/V (aliases Xs)
  const int bfv = get_bf(ws);
  const int b = blockIdx.x, n = b >> 5, y = b & 31;
  const int tid = threadIdx.x;
  const int w = tid >> 6, lane = tid & 63;      // 8 waves
  const int xb = lane & 15, quad = lane >> 4;
  const bf16* fb = (const bf16*)(ws + OF_FEATB);

  // ---- stage input rows y-1..y+1 zero-padded, transposed: Xs[r][1+x][c] ----
  const short8 zero8 = {0,0,0,0,0,0,0,0};
  if (tid < 192) {
    const int r = tid >> 6, xp = ((tid >> 5) & 1) * 33, c0 = (tid & 31)*8;
    *(short8*)&Xs[(r*34 + xp)*264 + c0] = zero8;
  }
#pragma unroll
  for (int u = 0; u < 6; ++u) {
    const int lin = u*512 + tid;
    const int cgrp = lin & 31, xl = (lin >> 5) & 31, r = lin >> 10;
    const int row = y + r - 1;
    short8 v = zero8;
    if ((unsigned)row < 32u)
      v = *(const short8*)&fb[((size_t)(n*PP + row*32 + xl))*CD + cgrp*8];
    *(short8*)&Xs[(r*34 + 1 + xl)*264 + cgrp*8] = v;
  }
  __syncthreads();

  // ---- conv MFMA K-loop: wave w owns o-tiles {2w, 2w+1}; lockstep taps (L1-resident) ----
  float4v a00 = (float4v)0.f, a01 = (float4v)0.f, a10 = (float4v)0.f, a11 = (float4v)0.f;
  const bf16* AW = (const bf16*)(ws + OF_AW);
  const int bvec = xb*264 + quad*8;   // vector part of B address

  short8 A0[3], A1[3], B0[3], B1[3];
#define PF(GI, S) do {                                                        \
    const int tap_ = (GI) >> 3, ch_ = (GI) & 7;                               \
    const int dy_ = (tap_ >= 6) ? 2 : ((tap_ >= 3) ? 1 : 0);                  \
    const int dx_ = tap_ - 3*dy_;                                             \
    const bf16* ap_ = AW + (((size_t)(tap_*8 + ch_)*16 + w*2)*64 + lane)*8;   \
    A0[S] = *(const short8*)&ap_[0];                                          \
    A1[S] = *(const short8*)&ap_[512];                                        \
    const short* bp_ = &Xs[(dy_*34 + dx_)*264 + ch_*32 + bvec];               \
    B0[S] = *(const short8*)&bp_[0];                                          \
    B1[S] = *(const short8*)&bp_[16*264];                                     \
  } while (0)

  PF(0, 0); PF(1, 1); PF(2, 2);
#pragma unroll
  for (int gi = 0; gi < 72; ++gi) {
    const int s = gi % 3;
    a00 = __builtin_amdgcn_mfma_f32_16x16x32_bf16(A0[s], B0[s], a00, 0, 0, 0);
    a01 = __builtin_amdgcn_mfma_f32_16x16x32_bf16(A0[s], B1[s], a01, 0, 0, 0);
    a10 = __builtin_amdgcn_mfma_f32_16x16x32_bf16(A1[s], B0[s], a10, 0, 0, 0);
    a11 = __builtin_amdgcn_mfma_f32_16x16x32_bf16(A1[s], B1[s], a11, 0, 0, 0);
    if (gi < 69) PF(gi + 3, s);
  }
#undef PF
  __syncthreads();   // Xs dead; red/AsT region safe to write

  // ---- in-register epilogue: lane holds (x0=xb: a00@o0, a10@o1), (x1=16+xb: a01@o0, a11@o1)
  const int o0 = w*32 + quad*4;   // a00/a01 channel base
  const int o1 = o0 + 16;         // a10/a11 channel base
  const int x0 = xb, x1 = 16 + xb;
  float v00[4], v01[4], v10[4], v11[4];
  {
    const int ry = (y == 0) ? 0 : ((y == 31) ? 2 : 1);
    const float* hnw = ws + OF_HNW;
    float4 hL0 = *(const float4*)&hnw[((size_t)(ry*3+0)*NB + n)*CD + o0];
    float4 hM0 = *(const float4*)&hnw[((size_t)(ry*3+1)*NB + n)*CD + o0];
    float4 hR0 = *(const float4*)&hnw[((size_t)(ry*3+2)*NB + n)*CD + o0];
    float4 hL1 = *(const float4*)&hnw[((size_t)(ry*3+0)*NB + n)*CD + o1];
    float4 hM1 = *(const float4*)&hnw[((size_t)(ry*3+1)*NB + n)*CD + o1];
    float4 hR1 = *(const float4*)&hnw[((size_t)(ry*3+2)*NB + n)*CD + o1];
    const float* scv = ws + OF_SCV + (size_t)(y*32)*CD;
    float4 s00 = *(const float4*)&scv[(size_t)x0*CD + o0];
    float4 s10 = *(const float4*)&scv[(size_t)x0*CD + o1];
    float4 s01 = *(const float4*)&scv[(size_t)x1*CD + o0];
    float4 s11 = *(const float4*)&scv[(size_t)x1*CD + o1];
    float4 h00 = (x0 == 0)  ? hL0 : hM0;
    float4 h10 = (x0 == 0)  ? hL1 : hM1;
    float4 h01 = (x1 == 31) ? hR0 : hM0;
    float4 h11 = (x1 == 31) ? hR1 : hM1;
    const float* s00p = (const float*)&s00; const float* s10p = (const float*)&s10;
    const float* s01p = (const float*)&s01; const float* s11p = (const float*)&s11;
    const float* h00p = (const float*)&h00; const float* h10p = (const float*)&h10;
    const float* h01p = (const float*)&h01; const float* h11p = (const float*)&h11;
#pragma unroll
    for (int r = 0; r < 4; ++r) {
      v00[r] = fmaxf(a00[r] + s00p[r] + h00p[r], 0.f);
      v10[r] = fmaxf(a10[r] + s10p[r] + h10p[r], 0.f);
      v01[r] = fmaxf(a01[r] + s01p[r] + h01p[r], 0.f);
      v11[r] = fmaxf(a11[r] + s11p[r] + h11p[r], 0.f);
    }
  }
  float sum0 = 0.f, sq0 = 0.f, sum1 = 0.f, sq1 = 0.f;
#pragma unroll
  for (int r = 0; r < 4; ++r) {
    sum0 += v00[r] + v10[r]; sq0 += v00[r]*v00[r] + v10[r]*v10[r];
    sum1 += v01[r] + v11[r]; sq1 += v01[r]*v01[r] + v11[r]*v11[r];
  }
  sum0 += __shfl_xor(sum0, 16, 64); sum0 += __shfl_xor(sum0, 32, 64);
  sq0  += __shfl_xor(sq0, 16, 64);  sq0  += __shfl_xor(sq0, 32, 64);
  sum1 += __shfl_xor(sum1, 16, 64); sum1 += __shfl_xor(sum1, 32, 64);
  sq1  += __shfl_xor(sq1, 16, 64);  sq1  += __shfl_xor(sq1, 32, 64);
  if (quad == 0) {
    red[x0*8 + w] = sum0;  red[256 + x0*8 + w] = sq0;
    red[x1*8 + w] = sum1;  red[256 + x1*8 + w] = sq1;
  }
  __syncthreads();
  if (tid < 32) {
    float ts = 0.f, tq = 0.f;
#pragma unroll
    for (int g = 0; g < 8; ++g) { ts += red[tid*8 + g]; tq += red[256 + tid*8 + g]; }
    float m = ts * (1.f/CD);
    float var = tq * (1.f/CD) - m*m;
    red[512 + tid] = m;
    red[544 + tid] = 1.f / sqrtf(var + 1e-5f);
  }
  __syncthreads();
  {
    const float m0 = red[512 + x0], r0 = red[544 + x0];
    const float m1 = red[512 + x1], r1 = red[544 + x1];
    float g0[4], b0[4], g1[4], b1[4];
#pragma unroll
    for (int r = 0; r < 4; ++r) {
      g0[r] = LD(mg, o0 + r, bfv); b0[r] = LD(mbv, o0 + r, bfv);
      g1[r] = LD(mg, o1 + r, bfv); b1[r] = LD(mbv, o1 + r, bfv);
    }
    short4v t00, t10, t01, t11;
#pragma unroll
    for (int r = 0; r < 4; ++r) {
      t00[r] = f2sh((v00[r] - m0)*r0*g0[r] + b0[r]);
      t10[r] = f2sh((v10[r] - m0)*r0*g1[r] + b1[r]);
      t01[r] = f2sh((v01[r] - m1)*r1*g0[r] + b0[r]);
      t11[r] = f2sh((v11[r] - m1)*r1*g1[r] + b1[r]);
    }
    *(short4v*)&AsT[x0*264 + o0] = t00;
    *(short4v*)&AsT[x0*264 + o1] = t10;
    *(short4v*)&AsT[x1*264 + o0] = t01;
    *(short4v*)&AsT[x1*264 + o1] = t11;
  }
  __syncthreads();   // AsT ready

  // ---- coalesced TB stream from AsT (t needed by k_oplin residual) ----
  {
    bf16* tp = (bf16*)(ws + OF_TB) + ((size_t)n*PP + (size_t)y*32)*CD;
    const int r = tid >> 4, c0 = (tid & 15)*16;
#pragma unroll
    for (int i = 0; i < 2; ++i) {
      short8 v = *(const short8*)&AsT[r*264 + c0 + i*8];
      *(short8*)&tp[(size_t)r*CD + c0 + i*8] = v;
    }
  }

  // ---- K and V projections from AsT: wave w owns c-tiles {2w, 2w+1} ----
  const short* PK = (const short*)(ws + OF_PK);
  const int p0 = y << 5;
#pragma unroll 1
  for (int G = 0; G < 2; ++G) {
    float4v ac2[2][2];
#pragma unroll
    for (int mt = 0; mt < 2; ++mt) { ac2[mt][0] = (float4v)0.f; ac2[mt][1] = (float4v)0.f; }
    mfma_core512(AsT, PK + (size_t)G*65536, w, lane, ac2);
    bf16* dst = (bf16*)(ws + (G ? OF_VVB : OF_KHB)) + ((size_t)n*PP + p0)*CD;
#pragma unroll
    for (int i = 0; i < 2; ++i) {
      const int c = (w*2 + i)*16 + xb;
      const float bias = LD(ipb, (size_t)(G+1)*256 + c, bfv);
#pragma unroll
      for (int mt = 0; mt < 2; ++mt)
#pragma unroll
        for (int r = 0; r < 4; ++r)
          dst[(size_t)(mt*16 + quad*4 + r)*CD + c] = f2bf(ac2[mt][i][r] + bias);
    }
  }
}

// FUSED attn+outproj+LN+lin1+lin2+LN+commit: 512 blocks x 512 thr. [R12 form]
// Block = pixel-pair {2b, 2b+1} x ALL 16 batches (rows = pp*16 + l).
// Attention via MFMA: QK = 4x mfma_16x16x32 per unit (waves 0-3);
// PV via mfma_16x16x32 with upper K-half of P zeroed; V rows clamped in-bounds
// ((quad&1) not quad): OOB LDS reads can decode as bf16 NaN -> 0*NaN = NaN (R11).
__global__ __launch_bounds__(512, 4) void k_oplin(const void* __restrict__ opb, const void* __restrict__ ng,
                                                  const void* __restrict__ nbv, const void* __restrict__ l1b,
                                                  const void* __restrict__ l2b, const void* __restrict__ nfg,
                                                  const void* __restrict__ nfb, const int* __restrict__ words,
                                                  int s, float* __restrict__ ws) {
  __shared__ float smem[15040];            // 60,160 B
  float* tile = smem;                      // [256][33] fp32 (aliases AsT/SQb)
  float* red  = smem + 8448;               // 1088 f
  short* AsT  = (short*)smem;              // [32][264] bf16 A-tile
  short* AsF  = (short*)(smem + 9536);     // [32][264] bf16 fea (aliases SVs)
  short* SQb  = (short*)smem;              // attn: [16][264] bf16 q rows (dead before AsT writes)
  short* SKs  = (short*)(smem + 4224);     // attn: [2][16][264] bf16 K rows
  short* SVs  = (short*)(smem + 9536);     // attn: [2][16][264] bf16 V rows
  short* Pb   = (short*)(smem + 13760);    // attn: [4][16][18] bf16 probs
  const int bf = get_bf(ws);
  const int b = blockIdx.x, p0 = b*2;
  const int tid = threadIdx.x, w = tid >> 6, lane = tid & 63;
  const int xb = lane & 15, quad = lane >> 4;
  const int o = tid & 255, half = tid >> 8;
  const short* PK = (const short*)(ws + OF_PK);
  const int c0i = (w*2 + 0)*16 + xb;
  const int c1i = (w*2 + 1)*16 + xb;

  // ---- stage SQ (bf16) + SK/SV (bf16) for both pixels ----
  {
    const int l = tid >> 5, c0 = (tid & 31)*8;
    const float* src = ws + OF_QH + ((size_t)(s*NB + l))*CD + c0;
    float4 q0 = *(const float4*)&src[0];
    float4 q1 = *(const float4*)&src[4];
    short8 t;
    t[0] = f2sh(q0.x); t[1] = f2sh(q0.y); t[2] = f2sh(q0.z); t[3] = f2sh(q0.w);
    t[4] = f2sh(q1.x); t[5] = f2sh(q1.y); t[6] = f2sh(q1.z); t[7] = f2sh(q1.w);
    *(short8*)&SQb[l*264 + c0] = t;
  }
  {
    const int row = tid >> 4, c0 = (tid & 15)*16;   // row = pp*16 + l
    const int pp = row >> 4, l = row & 15;
    const size_t srcoff = ((size_t)l*PP + (p0 + pp))*CD + c0;
    const bf16* khb = (const bf16*)(ws + OF_KHB);
    const bf16* vvb = (const bf16*)(ws + OF_VVB);
    *(short8*)&SKs[row*264 + c0]     = *(const short8*)&khb[srcoff];
    *(short8*)&SKs[row*264 + c0 + 8] = *(const short8*)&khb[srcoff + 8];
    *(short8*)&SVs[row*264 + c0]     = *(const short8*)&vvb[srcoff];
    *(short8*)&SVs[row*264 + c0 + 8] = *(const short8*)&vvb[srcoff + 8];
  }
  __syncthreads();

  // ---- QK^T + softmax: waves 0-3, one unit (pp=aq, head=hq) each ----
  if (w < 4) {
    const int aq = w >> 1, hq = w & 1;
    float4v sacc = (float4v)0.f;
#pragma unroll
    for (int ch = 0; ch < 4; ++ch) {
      short8 qa = *(const short8*)&SQb[xb*264 + hq*128 + ch*32 + quad*8];
      short8 kb = *(const short8*)&SKs[(aq*16 + xb)*264 + hq*128 + ch*32 + quad*8];
      sacc = __builtin_amdgcn_mfma_f32_16x16x32_bf16(qa, kb, sacc, 0, 0, 0);
    }
#pragma unroll
    for (int r = 0; r < 4; ++r) {
      float sc = sacc[r] * 0.08838834764831845f;
      float mx = sc;
      mx = fmaxf(mx, __shfl_xor(mx, 1, 64));
      mx = fmaxf(mx, __shfl_xor(mx, 2, 64));
      mx = fmaxf(mx, __shfl_xor(mx, 4, 64));
      mx = fmaxf(mx, __shfl_xor(mx, 8, 64));
      float e = __expf(sc - mx);
      float su = e;
      su += __shfl_xor(su, 1, 64);
      su += __shfl_xor(su, 2, 64);
      su += __shfl_xor(su, 4, 64);
      su += __shfl_xor(su, 8, 64);
      Pb[(w*16 + quad*4 + r)*18 + xb] = f2sh(e / su);
    }
  }
  __syncthreads();   // Pb ready; SQb dead

  // ---- PV: all 8 waves; wave = (unit u=w>>1, d-half dh=w&1); ao -> AsT ----
  {
    const int u = w >> 1, ap = u >> 1, hp = u & 1, dh = w & 1;
    short8 pa = {0,0,0,0,0,0,0,0};
    if (quad < 2) pa = *(const short8*)&Pb[(u*16 + xb)*18 + quad*8];
#pragma unroll
    for (int t = 0; t < 4; ++t) {
      const int dcol = hp*128 + dh*64 + t*16 + xb;
      short8 vb;
#pragma unroll
      for (int j = 0; j < 8; ++j)
        vb[j] = SVs[(ap*16 + (quad & 1)*8 + j)*264 + dcol];   // in-bounds; quad>=2 killed by zero A
      float4v acc = (float4v)0.f;
      acc = __builtin_amdgcn_mfma_f32_16x16x32_bf16(pa, vb, acc, 0, 0, 0);
#pragma unroll
      for (int r = 0; r < 4; ++r)
        AsT[(ap*16 + quad*4 + r)*264 + dcol] = f2sh(acc[r]);
    }
  }
  __syncthreads();   // AsT ready

  // ---- outproj: MFMA + residual folded in regs -> tile -> LN ----
  float vo[2][2][4];
  {
    float4v acc[2][2];
#pragma unroll
    for (int mt = 0; mt < 2; ++mt) { acc[mt][0] = (float4v)0.f; acc[mt][1] = (float4v)0.f; }
    mfma_core512(AsT, PK + (size_t)2*65536, w, lane, acc);
    const float bo0 = LD(opb, c0i, bf), bo1 = LD(opb, c1i, bf);
    const bf16* tb = (const bf16*)(ws + OF_TB);
#pragma unroll
    for (int mt = 0; mt < 2; ++mt)
#pragma unroll
      for (int r = 0; r < 4; ++r) {
        const int x = mt*16 + quad*4 + r;
        const size_t prow = ((size_t)(x & 15)*PP + p0 + (x >> 4))*CD;
        vo[mt][0][r] = acc[mt][0][r] + bo0 + bf2f(tb[prow + c0i]);
        vo[mt][1][r] = acc[mt][1][r] + bo1 + bf2f(tb[prow + c1i]);
      }
  }
  __syncthreads();   // AsT reads done before tile overwrite
#pragma unroll
  for (int i = 0; i < 2; ++i)
#pragma unroll
    for (int mt = 0; mt < 2; ++mt)
#pragma unroll
      for (int r = 0; r < 4; ++r)
        tile[((w*2 + i)*16 + xb)*33 + mt*16 + quad*4 + r] = vo[mt][i][r];
  __syncthreads();
  ln_reduce512(tile, red, tid);
  {
    const float g = LD(ng, o, bf), bb = LD(nbv, o, bf);
#pragma unroll
    for (int xi = 0; xi < 16; ++xi) {
      const int x = half*16 + xi;
      AsF[x*264 + o] = f2sh((tile[o*33 + x] - red[1024 + x]) * red[1056 + x] * g + bb);
    }
  }
  __syncthreads();   // AsF ready; tile dead

  // ---- lin1: fea -> relu -> AsT ----
  {
    float4v acc[2][2];
#pragma unroll
    for (int mt = 0; mt < 2; ++mt) { acc[mt][0] = (float4v)0.f; acc[mt][1] = (float4v)0.f; }
    mfma_core512(AsF, PK + (size_t)3*65536, w, lane, acc);
#pragma unroll
    for (int i = 0; i < 2; ++i) {
      const int c = (w*2 + i)*16 + xb;
      const float bias = LD(l1b, c, bf);
#pragma unroll
      for (int mt = 0; mt < 2; ++mt)
#pragma unroll
        for (int r = 0; r < 4; ++r)
          AsT[(mt*16 + quad*4 + r)*264 + c] = f2sh(fmaxf(acc[mt][i][r] + bias, 0.f));
    }
  }
  __syncthreads();

  // ---- lin2: MFMA + residual (AsF) folded in regs -> tile -> LN + commit ----
  {
    float4v acc[2][2];
#pragma unroll
    for (int mt = 0; mt < 2; ++mt) { acc[mt][0] = (float4v)0.f; acc[mt][1] = (float4v)0.f; }
    mfma_core512(AsT, PK + (size_t)4*65536, w, lane, acc);
    const float bl0 = LD(l2b, c0i, bf), bl1 = LD(l2b, c1i, bf);
#pragma unroll
    for (int mt = 0; mt < 2; ++mt)
#pragma unroll
      for (int r = 0; r < 4; ++r) {
        const int x = mt*16 + quad*4 + r;
        vo[mt][0][r] = acc[mt][0][r] + bl0 + sh2f(AsF[x*264 + c0i]);
        vo[mt][1][r] = acc[mt][1][r] + bl1 + sh2f(AsF[x*264 + c1i]);
      }
  }
  __syncthreads();   // AsT reads done before tile overwrite
#pragma unroll
  for (int i = 0; i < 2; ++i)
#pragma unroll
    for (int mt = 0; mt < 2; ++mt)
#pragma unroll
      for (int r = 0; r < 4; ++r)
        tile[((w*2 + i)*16 + xb)*33 + mt*16 + quad*4 + r] = vo[mt][i][r];
  __syncthreads();
  ln_reduce512(tile, red, tid);
  if (words[s] != 0) {
    const float g = LD(nfg, o, bf), b2 = LD(nfb, o, bf);
    bf16* fbd = (bf16*)(ws + OF_FEATB);
#pragma unroll
    for (int xi = 0; xi < 16; ++xi) {
      const int x = half*16 + xi;
      fbd[((size_t)(x & 15)*PP + p0 + (x >> 4))*CD + o] =
          f2bf((tile[o*33 + x] - red[1024 + x]) * red[1056 + x] * g + b2);
    }
  }
}

// output [n][c][p] from bf16 feat [n][p][c]
__global__ __launch_bounds__(256) void k_final(const float* __restrict__ ws, void* __restrict__ out) {
  const int bf = get_bf(ws);
  const size_t i = (size_t)blockIdx.x*256 + threadIdx.x;
  const int n = (int)(i >> 18), c = (int)((i >> 10) & 255), p = (int)(i & 1023);
  const bf16* fb = (const bf16*)(ws + OF_FEATB);
  float v = bf2f(fb[((size_t)(n*PP + p))*CD + c]);
  if (bf) ((bf16*)out)[i] = f2bf(v);
  else    ((float*)out)[i] = v;
}

extern "C" void kernel_launch(void* const* d_in, const int* in_sizes, int n_in,
                              void* d_out, int out_size, void* d_ws, size_t ws_size,
                              hipStream_t stream) {
  (void)in_sizes; (void)n_in; (void)out_size; (void)ws_size;
  const void* hn      = d_in[1];
  const void* feature = d_in[2];
  const void* emb     = d_in[3];
  const int*  words   = (const int*)d_in[4];
  const void* qw  = d_in[5];
  const void* qb  = d_in[6];
  const void* mw  = d_in[7];
  const void* mg  = d_in[8];
  const void* mb  = d_in[9];
  const void* ipw = d_in[10];
  const void* ipb = d_in[11];
  const void* opw = d_in[12];
  const void* opb = d_in[13];
  const void* ng  = d_in[14];
  const void* nb  = d_in[15];
  const void* l1w = d_in[16];
  const void* l1b = d_in[17];
  const void* l2w = d_in[18];
  const void* l2b = d_in[19];
  const void* nfg = d_in[20];
  const void* nfb = d_in[21];
  float* ws = (float*)d_ws;

  k_detect<<<1, 64, 0, stream>>>(mg, ws);
  k_init<<<NB*PP, 256, 0, stream>>>(feature, ws);
  k_qh<<<SEQL*NB, 256, 0, stream>>>(emb, qw, qb, ipw, ipb, ws);
  k_wregion<<<(9*CD*HND)/256, 256, 0, stream>>>(mw, ws);
  k_hnw<<<9*NB, 256, 0, stream>>>(hn, ws);
  k_sconv<<<PP, 256, 0, stream>>>(mw, ws);
  k_wpack<<<(9*8*16*64*8)/256, 256, 0, stream>>>(mw, ws);
  k_wpackB<<<(5*65536)/256, 256, 0, stream>>>(ipw, opw, l1w, l2w, ws);

  for (int s = 0; s < SEQL; ++s) {
    k_convkv<<<NB*32, 512, 0, stream>>>(mg, mb, ipb, ws);
    k_oplin<<<PP/2, 512, 0, stream>>>(opb, ng, nb, l1b, l2b, nfg, nfb, words, s, ws);
  }
  k_final<<<NB*CD*PP/256, 256, 0, stream>>>(ws, (void*)d_out);
}

// Round 15
// 1371.701 us; speedup vs baseline: 1.6196x; 1.0070x over previous
//
#include <hip/hip_runtime.h>
#include <hip/hip_bf16.h>
#include <cstddef>

typedef __hip_bfloat16 bf16;
typedef short short8 __attribute__((ext_vector_type(8)));
typedef short short4v __attribute__((ext_vector_type(4)));
typedef float float4v __attribute__((ext_vector_type(4)));
#define DEV static __device__ __forceinline__

constexpr int NB = 16;     // batch
constexpr int SEQL = 20;
constexpr int CD = 256;    // VD
constexpr int PP = 1024;   // 32*32
constexpr int HND = 512;
constexpr int EMBD = 300;
constexpr int CIN = 776;   // 256 + 8 + 512

// ---- workspace layout (float element offsets); bf16 buffers are [n][p][c] ----
constexpr size_t SZB = (size_t)NB * PP * CD / 2;             // floats per bf16 NPC buffer
constexpr size_t OF_FEATB = 0;                               // running feature (bf16)
constexpr size_t OF_TB   = 1*SZB;                            // t (bf16)
constexpr size_t OF_QH   = 7*SZB;                            // qh [s][n][c] fp32
constexpr size_t OF_HNW  = OF_QH  + (size_t)SEQL*NB*CD;      // hnW [r][n][o] fp32
constexpr size_t OF_SCV  = OF_HNW + (size_t)9*NB*CD;         // sconv [p][o] fp32
constexpr size_t OF_WRG  = OF_SCV + (size_t)PP*CD;           // W_region [r][o][c] fp32
constexpr size_t OF_AW   = OF_WRG + (size_t)9*CD*HND;        // conv W A-frags (589,824 bf16)
constexpr size_t OF_PK   = OF_AW  + (size_t)294912;          // linear W B-frags: 5 x 65,536 bf16
constexpr size_t OF_FLAG = OF_PK  + (size_t)163840;          // dtype flag

DEV float bf2f(bf16 v) { return __bfloat162float(v); }
DEV bf16 f2bf(float v) { return __float2bfloat16(v); }
DEV float sh2f(short v) { bf16 t; *(short*)&t = v; return __bfloat162float(t); }
DEV short f2sh(float v) { bf16 t = f2bf(v); return *(const short*)&t; }

DEV float LD(const void* p, size_t i, int bf) {
  return bf ? __bfloat162float(((const bf16*)p)[i]) : ((const float*)p)[i];
}
DEV int get_bf(const float* ws) { return ((const int*)ws)[OF_FLAG]; }

__global__ void k_detect(const void* g, float* ws) {
  if (threadIdx.x == 0 && blockIdx.x == 0) {
    unsigned w = *(const unsigned*)g;
    ((int*)ws)[OF_FLAG] = ((w & 0xFFFFu) != 0u) ? 1 : 0;
  }
}

// LN reduction, 512 threads: tile[o][x] stride 33; red[1024+x]=mean, red[1056+x]=rstd
// NOTE (R9 lesson): do NOT replace with __shfl chains — shfl = ds_swizzle (LDS pipe).
DEV void ln_reduce512(const float* tile, float* red, int tid) {
  const int x = tid & 31, seg = tid >> 5;   // 16 segs of 16 channels
  float s = 0.f, sq = 0.f;
#pragma unroll
  for (int i = 0; i < 16; ++i) {
    float v = tile[(seg*16 + i)*33 + x];
    s += v; sq += v*v;
  }
  red[seg*32 + x] = s;
  red[512 + seg*32 + x] = sq;
  __syncthreads();
  if (tid < 32) {
    float ts = 0.f, tq = 0.f;
#pragma unroll
    for (int g = 0; g < 16; ++g) { ts += red[g*32 + tid]; tq += red[512 + g*32 + tid]; }
    float m = ts * (1.f/CD);
    float var = tq * (1.f/CD) - m*m;
    red[1024 + tid] = m;
    red[1056 + tid] = 1.f / sqrtf(var + 1e-5f);
  }
  __syncthreads();
}

// 512-thr linear core: ALL 16 global B-frags preloaded up front.
// Layout (production-validated): A m=lane&15, k=(lane>>4)*8+j; B n=lane&15, same k;
// D m=(lane>>4)*4+r, n=lane&15.
DEV void mfma_core512(const short* __restrict__ As, const short* __restrict__ PKg,
                      int w, int lane, float4v acc[2][2]) {
  const int xb = lane & 15, quad = lane >> 4;
  const short* base = PKg + lane*8;
  short8 b0[8], b1[8];
#pragma unroll
  for (int ch = 0; ch < 8; ++ch) {
    b0[ch] = *(const short8*)&base[(size_t)((w*2+0)*8 + ch)*512];
    b1[ch] = *(const short8*)&base[(size_t)((w*2+1)*8 + ch)*512];
  }
#pragma unroll
  for (int ch = 0; ch < 8; ++ch) {
    short8 a0 = *(const short8*)&As[xb*264 + ch*32 + quad*8];
    short8 a1 = *(const short8*)&As[(16+xb)*264 + ch*32 + quad*8];
    acc[0][0] = __builtin_amdgcn_mfma_f32_16x16x32_bf16(a0, b0[ch], acc[0][0], 0, 0, 0);
    acc[0][1] = __builtin_amdgcn_mfma_f32_16x16x32_bf16(a0, b1[ch], acc[0][1], 0, 0, 0);
    acc[1][0] = __builtin_amdgcn_mfma_f32_16x16x32_bf16(a1, b0[ch], acc[1][0], 0, 0, 0);
    acc[1][1] = __builtin_amdgcn_mfma_f32_16x16x32_bf16(a1, b1[ch], acc[1][1], 0, 0, 0);
  }
}

// ---------------- prep kernels ----------------

__global__ __launch_bounds__(256) void k_init(const void* __restrict__ f, float* __restrict__ ws) {
  const int bf = get_bf(ws);
  const int b = blockIdx.x;
  const int n = b >> 10, p = b & 1023;
  const int c = threadIdx.x;
  bf16* fb = (bf16*)(ws + OF_FEATB);
  fb[(size_t)b*CD + c] = f2bf(LD(f, ((size_t)n*CD + c)*PP + p, bf));
}

__global__ __launch_bounds__(256) void k_qh(const void* __restrict__ emb, const void* __restrict__ qw,
                                            const void* __restrict__ qb, const void* __restrict__ ipw,
                                            const void* __restrict__ ipb, float* __restrict__ ws) {
  const int bf = get_bf(ws);
  const int b = blockIdx.x, s = b / NB, n = b % NB;
  const int o = threadIdx.x;
  __shared__ float se[EMBD];
  __shared__ float sq[CD];
  for (int i = o; i < EMBD; i += CD) se[i] = LD(emb, ((size_t)n*SEQL + s)*EMBD + i, bf);
  __syncthreads();
  float a = LD(qb, o, bf);
  if (bf) {
    const bf16* wr = (const bf16*)qw + (size_t)o*EMBD;
    for (int c = 0; c < EMBD; ++c) a += se[c]*bf2f(wr[c]);
  } else {
    const float* wr = (const float*)qw + (size_t)o*EMBD;
    for (int c = 0; c < EMBD; ++c) a += se[c]*wr[c];
  }
  sq[o] = fmaxf(a, 0.f);
  __syncthreads();
  float a2 = LD(ipb, o, bf);
  if (bf) {
    const bf16* wq = (const bf16*)ipw + (size_t)o*CD;
    for (int c = 0; c < CD; ++c) a2 += sq[c]*bf2f(wq[c]);
  } else {
    const float* wq = (const float*)ipw + (size_t)o*CD;
    for (int c = 0; c < CD; ++c) a2 += sq[c]*wq[c];
  }
  ws[OF_QH + ((size_t)s*NB + n)*CD + o] = a2;
}

__global__ __launch_bounds__(256) void k_wregion(const void* __restrict__ mw, float* __restrict__ ws) {
  const int bf = get_bf(ws);
  const int gid = blockIdx.x*256 + threadIdx.x;
  const int c = gid & (HND-1);
  const int o = (gid >> 9) & (CD-1);
  const int r = gid >> 17;
  const int ry = r/3, rx = r%3;
  float s = 0.f;
  for (int dy = 0; dy < 3; ++dy) {
    if (ry == 0 && dy == 0) continue;
    if (ry == 2 && dy == 2) continue;
    for (int dx = 0; dx < 3; ++dx) {
      if (rx == 0 && dx == 0) continue;
      if (rx == 2 && dx == 2) continue;
      s += LD(mw, ((size_t)o*CIN + 264 + c)*9 + dy*3 + dx, bf);
    }
  }
  ws[OF_WRG + gid] = s;
}

__global__ __launch_bounds__(256) void k_hnw(const void* __restrict__ hn, float* __restrict__ ws) {
  const int bf = get_bf(ws);
  const int b = blockIdx.x, r = b / NB, n = b % NB;
  const int o = threadIdx.x;
  __shared__ float sh[HND];
  for (int i = o; i < HND; i += CD) sh[i] = LD(hn, (size_t)n*HND + i, bf);
  __syncthreads();
  const float* wr = ws + OF_WRG + ((size_t)r*CD + o)*HND;
  float a = 0.f;
  for (int c = 0; c < HND; ++c) a += sh[c]*wr[c];
  ws[OF_HNW + ((size_t)r*NB + n)*CD + o] = a;
}

DEV float spat(int c, int yy, int xx) {
  switch (c) {
    case 0: return xx*(1.f/16) - 1.f;
    case 1: return yy*(1.f/16) - 1.f;
    case 2: return (xx+1)*(1.f/16) - 1.f;
    case 3: return (yy+1)*(1.f/16) - 1.f;
    case 4: return (xx+0.5f)*(1.f/16) - 1.f;
    case 5: return (yy+0.5f)*(1.f/16) - 1.f;
    default: return 1.f/32;
  }
}

__global__ __launch_bounds__(256) void k_sconv(const void* __restrict__ mw, float* __restrict__ ws) {
  const int bf = get_bf(ws);
  const int p = blockIdx.x, o = threadIdx.x;
  const int y = p >> 5, x = p & 31;
  float a = 0.f;
  for (int c = 0; c < 8; ++c)
    for (int dy = 0; dy < 3; ++dy) {
      int yy = y + dy - 1; if ((unsigned)yy >= 32u) continue;
      for (int dx = 0; dx < 3; ++dx) {
        int xx = x + dx - 1; if ((unsigned)xx >= 32u) continue;
        a += LD(mw, ((size_t)o*CIN + 256 + c)*9 + dy*3 + dx, bf) * spat(c, yy, xx);
      }
    }
  ws[OF_SCV + (size_t)p*CD + o] = a;
}

// conv feat weights -> MFMA A-frag order: AW[it=tap*8+ch][mt][lane][8]
__global__ __launch_bounds__(256) void k_wpack(const void* __restrict__ mw, float* __restrict__ ws) {
  const int bf = get_bf(ws);
  const int idx = blockIdx.x*256 + threadIdx.x;
  const int j = idx & 7;
  const int lane = (idx >> 3) & 63;
  const int mt = (idx >> 9) & 15;
  const int ch = (idx >> 13) & 7;
  const int tap = idx >> 16;
  const int o = mt*16 + (lane & 15);
  const int c = ch*32 + (lane >> 4)*8 + j;
  bf16* aw = (bf16*)(ws + OF_AW);
  aw[idx] = f2bf(LD(mw, ((size_t)o*CIN + c)*9 + tap, bf));
}

// linear weights -> MFMA B-frag order: PK[g][nt][ch][lane][8]; g: 0=Wk 1=Wv 2=Wo 3=W1 4=W2
__global__ __launch_bounds__(256) void k_wpackB(const void* __restrict__ ipw, const void* __restrict__ opw,
                                                const void* __restrict__ l1w, const void* __restrict__ l2w,
                                                float* __restrict__ ws) {
  const int bf = get_bf(ws);
  const int idx = blockIdx.x*256 + threadIdx.x;
  const int j = idx & 7;
  const int lane = (idx >> 3) & 63;
  const int ch = (idx >> 9) & 7;
  const int nt = (idx >> 12) & 15;
  const int g = idx >> 16;
  const int o = nt*16 + (lane & 15);
  const int k = ch*32 + (lane >> 4)*8 + j;
  float v;
  switch (g) {
    case 0: v = LD(ipw, ((size_t)(256 + o))*CD + k, bf); break;
    case 1: v = LD(ipw, ((size_t)(512 + o))*CD + k, bf); break;
    case 2: v = LD(opw, (size_t)o*CD + k, bf);           break;
    case 3: v = LD(l1w, (size_t)o*CD + k, bf);           break;
    default: v = LD(l2w, (size_t)o*CD + k, bf);          break;
  }
  ((bf16*)(ws + OF_PK))[idx] = f2bf(v);
}

// ---------------- per-step kernels ----------------

// FUSED conv+LN: 512 blocks x 512 thr, block=(n,y). [R15: K/V projection REMOVED —
// k_oplin recomputes K/V locally from the t-tile it stages anyway, killing the
// 33.6 MB/step KHB/VVB global round-trip.]
// NOTE (R5/R13): 2-row reuse variants fail (occupancy / register spills).
__global__ __launch_bounds__(512, 4) void k_convkv(const void* __restrict__ mg, const void* __restrict__ mbv,
                                                   const void* __restrict__ ipb, float* __restrict__ ws) {
  __shared__ float smem[13464];            // 53,856 B
  short* Xs = (short*)smem;                // conv input stage (dead after conv)
  float* red  = smem;                      // aliases Xs: [0..255] sums, [256..511] sqsums, [512..575] stats
  short* AsT  = (short*)(smem + 576);      // t staging (TB stream source; aliases Xs)
  const int bfv = get_bf(ws);
  const int b = blockIdx.x, n = b >> 5, y = b & 31;
  const int tid = threadIdx.x;
  const int w = tid >> 6, lane = tid & 63;      // 8 waves
  const int xb = lane & 15, quad = lane >> 4;
  const bf16* fb = (const bf16*)(ws + OF_FEATB);
  (void)ipb;

  // ---- stage input rows y-1..y+1 zero-padded, transposed: Xs[r][1+x][c] ----
  const short8 zero8 = {0,0,0,0,0,0,0,0};
  if (tid < 192) {
    const int r = tid >> 6, xp = ((tid >> 5) & 1) * 33, c0 = (tid & 31)*8;
    *(short8*)&Xs[(r*34 + xp)*264 + c0] = zero8;
  }
#pragma unroll
  for (int u = 0; u < 6; ++u) {
    const int lin = u*512 + tid;
    const int cgrp = lin & 31, xl = (lin >> 5) & 31, r = lin >> 10;
    const int row = y + r - 1;
    short8 v = zero8;
    if ((unsigned)row < 32u)
      v = *(const short8*)&fb[((size_t)(n*PP + row*32 + xl))*CD + cgrp*8];
    *(short8*)&Xs[(r*34 + 1 + xl)*264 + cgrp*8] = v;
  }
  __syncthreads();

  // ---- conv MFMA K-loop: wave w owns o-tiles {2w, 2w+1}; lockstep taps (L1-resident) ----
  float4v a00 = (float4v)0.f, a01 = (float4v)0.f, a10 = (float4v)0.f, a11 = (float4v)0.f;
  const bf16* AW = (const bf16*)(ws + OF_AW);
  const int bvec = xb*264 + quad*8;   // vector part of B address

  short8 A0[3], A1[3], B0[3], B1[3];
#define PF(GI, S) do {                                                        \
    const int tap_ = (GI) >> 3, ch_ = (GI) & 7;                               \
    const int dy_ = (tap_ >= 6) ? 2 : ((tap_ >= 3) ? 1 : 0);                  \
    const int dx_ = tap_ - 3*dy_;                                             \
    const bf16* ap_ = AW + (((size_t)(tap_*8 + ch_)*16 + w*2)*64 + lane)*8;   \
    A0[S] = *(const short8*)&ap_[0];                                          \
    A1[S] = *(const short8*)&ap_[512];                                        \
    const short* bp_ = &Xs[(dy_*34 + dx_)*264 + ch_*32 + bvec];               \
    B0[S] = *(const short8*)&bp_[0];                                          \
    B1[S] = *(const short8*)&bp_[16*264];                                     \
  } while (0)

  PF(0, 0); PF(1, 1); PF(2, 2);
#pragma unroll
  for (int gi = 0; gi < 72; ++gi) {
    const int s = gi % 3;
    a00 = __builtin_amdgcn_mfma_f32_16x16x32_bf16(A0[s], B0[s], a00, 0, 0, 0);
    a01 = __builtin_amdgcn_mfma_f32_16x16x32_bf16(A0[s], B1[s], a01, 0, 0, 0);
    a10 = __builtin_amdgcn_mfma_f32_16x16x32_bf16(A1[s], B0[s], a10, 0, 0, 0);
    a11 = __builtin_amdgcn_mfma_f32_16x16x32_bf16(A1[s], B1[s], a11, 0, 0, 0);
    if (gi < 69) PF(gi + 3, s);
  }
#undef PF
  __syncthreads();   // Xs dead; red/AsT region safe to write

  // ---- in-register epilogue ----
  const int o0 = w*32 + quad*4;
  const int o1 = o0 + 16;
  const int x0 = xb, x1 = 16 + xb;
  float v00[4], v01[4], v10[4], v11[4];
  {
    const int ry = (y == 0) ? 0 : ((y == 31) ? 2 : 1);
    const float* hnw = ws + OF_HNW;
    float4 hL0 = *(const float4*)&hnw[((size_t)(ry*3+0)*NB + n)*CD + o0];
    float4 hM0 = *(const float4*)&hnw[((size_t)(ry*3+1)*NB + n)*CD + o0];
    float4 hR0 = *(const float4*)&hnw[((size_t)(ry*3+2)*NB + n)*CD + o0];
    float4 hL1 = *(const float4*)&hnw[((size_t)(ry*3+0)*NB + n)*CD + o1];
    float4 hM1 = *(const float4*)&hnw[((size_t)(ry*3+1)*NB + n)*CD + o1];
    float4 hR1 = *(const float4*)&hnw[((size_t)(ry*3+2)*NB + n)*CD + o1];
    const float* scv = ws + OF_SCV + (size_t)(y*32)*CD;
    float4 s00 = *(const float4*)&scv[(size_t)x0*CD + o0];
    float4 s10 = *(const float4*)&scv[(size_t)x0*CD + o1];
    float4 s01 = *(const float4*)&scv[(size_t)x1*CD + o0];
    float4 s11 = *(const float4*)&scv[(size_t)x1*CD + o1];
    float4 h00 = (x0 == 0)  ? hL0 : hM0;
    float4 h10 = (x0 == 0)  ? hL1 : hM1;
    float4 h01 = (x1 == 31) ? hR0 : hM0;
    float4 h11 = (x1 == 31) ? hR1 : hM1;
    const float* s00p = (const float*)&s00; const float* s10p = (const float*)&s10;
    const float* s01p = (const float*)&s01; const float* s11p = (const float*)&s11;
    const float* h00p = (const float*)&h00; const float* h10p = (const float*)&h10;
    const float* h01p = (const float*)&h01; const float* h11p = (const float*)&h11;
#pragma unroll
    for (int r = 0; r < 4; ++r) {
      v00[r] = fmaxf(a00[r] + s00p[r] + h00p[r], 0.f);
      v10[r] = fmaxf(a10[r] + s10p[r] + h10p[r], 0.f);
      v01[r] = fmaxf(a01[r] + s01p[r] + h01p[r], 0.f);
      v11[r] = fmaxf(a11[r] + s11p[r] + h11p[r], 0.f);
    }
  }
  float sum0 = 0.f, sq0 = 0.f, sum1 = 0.f, sq1 = 0.f;
#pragma unroll
  for (int r = 0; r < 4; ++r) {
    sum0 += v00[r] + v10[r]; sq0 += v00[r]*v00[r] + v10[r]*v10[r];
    sum1 += v01[r] + v11[r]; sq1 += v01[r]*v01[r] + v11[r]*v11[r];
  }
  sum0 += __shfl_xor(sum0, 16, 64); sum0 += __shfl_xor(sum0, 32, 64);
  sq0  += __shfl_xor(sq0, 16, 64);  sq0  += __shfl_xor(sq0, 32, 64);
  sum1 += __shfl_xor(sum1, 16, 64); sum1 += __shfl_xor(sum1, 32, 64);
  sq1  += __shfl_xor(sq1, 16, 64);  sq1  += __shfl_xor(sq1, 32, 64);
  if (quad == 0) {
    red[x0*8 + w] = sum0;  red[256 + x0*8 + w] = sq0;
    red[x1*8 + w] = sum1;  red[256 + x1*8 + w] = sq1;
  }
  __syncthreads();
  if (tid < 32) {
    float ts = 0.f, tq = 0.f;
#pragma unroll
    for (int g = 0; g < 8; ++g) { ts += red[tid*8 + g]; tq += red[256 + tid*8 + g]; }
    float m = ts * (1.f/CD);
    float var = tq * (1.f/CD) - m*m;
    red[512 + tid] = m;
    red[544 + tid] = 1.f / sqrtf(var + 1e-5f);
  }
  __syncthreads();
  {
    const float m0 = red[512 + x0], r0 = red[544 + x0];
    const float m1 = red[512 + x1], r1 = red[544 + x1];
    float g0[4], b0[4], g1[4], b1[4];
#pragma unroll
    for (int r = 0; r < 4; ++r) {
      g0[r] = LD(mg, o0 + r, bfv); b0[r] = LD(mbv, o0 + r, bfv);
      g1[r] = LD(mg, o1 + r, bfv); b1[r] = LD(mbv, o1 + r, bfv);
    }
    short4v t00, t10, t01, t11;
#pragma unroll
    for (int r = 0; r < 4; ++r) {
      t00[r] = f2sh((v00[r] - m0)*r0*g0[r] + b0[r]);
      t10[r] = f2sh((v10[r] - m0)*r0*g1[r] + b1[r]);
      t01[r] = f2sh((v01[r] - m1)*r1*g0[r] + b0[r]);
      t11[r] = f2sh((v11[r] - m1)*r1*g1[r] + b1[r]);
    }
    *(short4v*)&AsT[x0*264 + o0] = t00;
    *(short4v*)&AsT[x0*264 + o1] = t10;
    *(short4v*)&AsT[x1*264 + o0] = t01;
    *(short4v*)&AsT[x1*264 + o1] = t11;
  }
  __syncthreads();   // AsT ready

  // ---- coalesced TB stream from AsT (sole output besides nothing else now) ----
  {
    bf16* tp = (bf16*)(ws + OF_TB) + ((size_t)n*PP + (size_t)y*32)*CD;
    const int r = tid >> 4, c0 = (tid & 15)*16;
#pragma unroll
    for (int i = 0; i < 2; ++i) {
      short8 v = *(const short8*)&AsT[r*264 + c0 + i*8];
      *(short8*)&tp[(size_t)r*CD + c0 + i*8] = v;
    }
  }
}

// FUSED KV+attn+outproj+LN+lin1+lin2+LN+commit: 512 blocks x 512 thr. [R15]
// Block = pixel-pair {2b, 2b+1} x ALL 16 batches (rows x = pp*16 + l).
// Stages t-tile (Tt) once from TB; computes K/V locally (2 GEMMs, identical math
// to the removed convkv phase); residual read from Tt LDS. Attention via MFMA
// (R12, with the 0*NaN OOB guard).
__global__ __launch_bounds__(512, 4) void k_oplin(const void* __restrict__ ipb, const void* __restrict__ opb,
                                                  const void* __restrict__ ng, const void* __restrict__ nbv,
                                                  const void* __restrict__ l1b, const void* __restrict__ l2b,
                                                  const void* __restrict__ nfg, const void* __restrict__ nfb,
                                                  const int* __restrict__ words, int s, float* __restrict__ ws) {
  __shared__ float smem[18560];            // 74,240 B (2 blocks/CU: 148.5KB <= 160KB)
  float* tile = smem;                      // [256][33] fp32 [0..8448)
  float* red  = smem + 8448;               // [8448..9536)
  short* AsT  = (short*)smem;              // [32][264] bf16 [0..4224f)
  short* AsF  = (short*)(smem + 9536);     // [32][264] bf16 (aliases SVs)
  short* SQb  = (short*)smem;              // attn q rows [0..4224f), dead before AsT writes
  short* SKs  = (short*)(smem + 4224);     // K rows [4224..8448)
  short* SVs  = (short*)(smem + 9536);     // V rows [9536..13760)
  short* Pb   = (short*)(smem + 13760);    // probs [13760..14336)
  short* Tt   = (short*)(smem + 14336);    // t-tile [32][264] bf16 [14336..18560) — live whole kernel
  const int bf = get_bf(ws);
  const int b = blockIdx.x, p0 = b*2;
  const int tid = threadIdx.x, w = tid >> 6, lane = tid & 63;
  const int xb = lane & 15, quad = lane >> 4;
  const int o = tid & 255, half = tid >> 8;
  const short* PK = (const short*)(ws + OF_PK);
  const int c0i = (w*2 + 0)*16 + xb;
  const int c1i = (w*2 + 1)*16 + xb;

  // ---- stage SQ (bf16) + Tt (t rows for both pixels, from TB) ----
  {
    const int l = tid >> 5, c0 = (tid & 31)*8;
    const float* src = ws + OF_QH + ((size_t)(s*NB + l))*CD + c0;
    float4 q0 = *(const float4*)&src[0];
    float4 q1 = *(const float4*)&src[4];
    short8 t;
    t[0] = f2sh(q0.x); t[1] = f2sh(q0.y); t[2] = f2sh(q0.z); t[3] = f2sh(q0.w);
    t[4] = f2sh(q1.x); t[5] = f2sh(q1.y); t[6] = f2sh(q1.z); t[7] = f2sh(q1.w);
    *(short8*)&SQb[l*264 + c0] = t;
  }
  {
    const int row = tid >> 4, c0 = (tid & 15)*16;   // row x = pp*16 + l
    const int pp = row >> 4, l = row & 15;
    const size_t srcoff = ((size_t)l*PP + (p0 + pp))*CD + c0;
    const bf16* tb = (const bf16*)(ws + OF_TB);
    *(short8*)&Tt[row*264 + c0]     = *(const short8*)&tb[srcoff];
    *(short8*)&Tt[row*264 + c0 + 8] = *(const short8*)&tb[srcoff + 8];
  }
  __syncthreads();

  // ---- K/V projections from Tt (identical math to removed convkv phase) ----
#pragma unroll 1
  for (int G = 0; G < 2; ++G) {
    float4v acc[2][2];
#pragma unroll
    for (int mt = 0; mt < 2; ++mt) { acc[mt][0] = (float4v)0.f; acc[mt][1] = (float4v)0.f; }
    mfma_core512(Tt, PK + (size_t)G*65536, w, lane, acc);
    short* dstS = G ? SVs : SKs;
#pragma unroll
    for (int i = 0; i < 2; ++i) {
      const int c = (w*2 + i)*16 + xb;
      const float bias = LD(ipb, (size_t)(G+1)*256 + c, bf);
#pragma unroll
      for (int mt = 0; mt < 2; ++mt)
#pragma unroll
        for (int r = 0; r < 4; ++r)
          dstS[(mt*16 + quad*4 + r)*264 + c] = f2sh(acc[mt][i][r] + bias);
    }
  }
  __syncthreads();   // SKs/SVs ready

  // ---- QK^T + softmax: waves 0-3, one unit (pp=aq, head=hq) each ----
  if (w < 4) {
    const int aq = w >> 1, hq = w & 1;
    float4v sacc = (float4v)0.f;
#pragma unroll
    for (int ch = 0; ch < 4; ++ch) {
      short8 qa = *(const short8*)&SQb[xb*264 + hq*128 + ch*32 + quad*8];
      short8 kb = *(const short8*)&SKs[(aq*16 + xb)*264 + hq*128 + ch*32 + quad*8];
      sacc = __builtin_amdgcn_mfma_f32_16x16x32_bf16(qa, kb, sacc, 0, 0, 0);
    }
#pragma unroll
    for (int r = 0; r < 4; ++r) {
      float sc = sacc[r] * 0.08838834764831845f;
      float mx = sc;
      mx = fmaxf(mx, __shfl_xor(mx, 1, 64));
      mx = fmaxf(mx, __shfl_xor(mx, 2, 64));
      mx = fmaxf(mx, __shfl_xor(mx, 4, 64));
      mx = fmaxf(mx, __shfl_xor(mx, 8, 64));
      float e = __expf(sc - mx);
      float su = e;
      su += __shfl_xor(su, 1, 64);
      su += __shfl_xor(su, 2, 64);
      su += __shfl_xor(su, 4, 64);
      su += __shfl_xor(su, 8, 64);
      Pb[(w*16 + quad*4 + r)*18 + xb] = f2sh(e / su);
    }
  }
  __syncthreads();   // Pb ready; SQb dead

  // ---- PV: all 8 waves; wave = (unit u=w>>1, d-half dh=w&1); ao -> AsT ----
  {
    const int u = w >> 1, ap = u >> 1, hp = u & 1, dh = w & 1;
    short8 pa = {0,0,0,0,0,0,0,0};
    if (quad < 2) pa = *(const short8*)&Pb[(u*16 + xb)*18 + quad*8];
#pragma unroll
    for (int t = 0; t < 4; ++t) {
      const int dcol = hp*128 + dh*64 + t*16 + xb;
      short8 vb;
#pragma unroll
      for (int j = 0; j < 8; ++j)
        vb[j] = SVs[(ap*16 + (quad & 1)*8 + j)*264 + dcol];   // in-bounds; quad>=2 killed by zero A
      float4v acc = (float4v)0.f;
      acc = __builtin_amdgcn_mfma_f32_16x16x32_bf16(pa, vb, acc, 0, 0, 0);
#pragma unroll
      for (int r = 0; r < 4; ++r)
        AsT[(ap*16 + quad*4 + r)*264 + dcol] = f2sh(acc[r]);
    }
  }
  __syncthreads();   // AsT ready

  // ---- outproj: MFMA + residual (Tt LDS) folded in regs -> tile -> LN ----
  float vo[2][2][4];
  {
    float4v acc[2][2];
#pragma unroll
    for (int mt = 0; mt < 2; ++mt) { acc[mt][0] = (float4v)0.f; acc[mt][1] = (float4v)0.f; }
    mfma_core512(AsT, PK + (size_t)2*65536, w, lane, acc);
    const float bo0 = LD(opb, c0i, bf), bo1 = LD(opb, c1i, bf);
#pragma unroll
    for (int mt = 0; mt < 2; ++mt)
#pragma unroll
      for (int r = 0; r < 4; ++r) {
        const int x = mt*16 + quad*4 + r;
        vo[mt][0][r] = acc[mt][0][r] + bo0 + sh2f(Tt[x*264 + c0i]);
        vo[mt][1][r] = acc[mt][1][r] + bo1 + sh2f(Tt[x*264 + c1i]);
      }
  }
  __syncthreads();   // AsT reads done before tile overwrite
#pragma unroll
  for (int i = 0; i < 2; ++i)
#pragma unroll
    for (int mt = 0; mt < 2; ++mt)
#pragma unroll
      for (int r = 0; r < 4; ++r)
        tile[((w*2 + i)*16 + xb)*33 + mt*16 + quad*4 + r] = vo[mt][i][r];
  __syncthreads();
  ln_reduce512(tile, red, tid);
  {
    const float g = LD(ng, o, bf), bb = LD(nbv, o, bf);
#pragma unroll
    for (int xi = 0; xi < 16; ++xi) {
      const int x = half*16 + xi;
      AsF[x*264 + o] = f2sh((tile[o*33 + x] - red[1024 + x]) * red[1056 + x] * g + bb);
    }
  }
  __syncthreads();   // AsF ready; tile dead

  // ---- lin1: fea -> relu -> AsT ----
  {
    float4v acc[2][2];
#pragma unroll
    for (int mt = 0; mt < 2; ++mt) { acc[mt][0] = (float4v)0.f; acc[mt][1] = (float4v)0.f; }
    mfma_core512(AsF, PK + (size_t)3*65536, w, lane, acc);
#pragma unroll
    for (int i = 0; i < 2; ++i) {
      const int c = (w*2 + i)*16 + xb;
      const float bias = LD(l1b, c, bf);
#pragma unroll
      for (int mt = 0; mt < 2; ++mt)
#pragma unroll
        for (int r = 0; r < 4; ++r)
          AsT[(mt*16 + quad*4 + r)*264 + c] = f2sh(fmaxf(acc[mt][i][r] + bias, 0.f));
    }
  }
  __syncthreads();

  // ---- lin2: MFMA + residual (AsF) folded in regs -> tile -> LN + commit ----
  {
    float4v acc[2][2];
#pragma unroll
    for (int mt = 0; mt < 2; ++mt) { acc[mt][0] = (float4v)0.f; acc[mt][1] = (float4v)0.f; }
    mfma_core512(AsT, PK + (size_t)4*65536, w, lane, acc);
    const float bl0 = LD(l2b, c0i, bf), bl1 = LD(l2b, c1i, bf);
#pragma unroll
    for (int mt = 0; mt < 2; ++mt)
#pragma unroll
      for (int r = 0; r < 4; ++r) {
        const int x = mt*16 + quad*4 + r;
        vo[mt][0][r] = acc[mt][0][r] + bl0 + sh2f(AsF[x*264 + c0i]);
        vo[mt][1][r] = acc[mt][1][r] + bl1 + sh2f(AsF[x*264 + c1i]);
      }
  }
  __syncthreads();   // AsT reads done before tile overwrite
#pragma unroll
  for (int i = 0; i < 2; ++i)
#pragma unroll
    for (int mt = 0; mt < 2; ++mt)
#pragma unroll
      for (int r = 0; r < 4; ++r)
        tile[((w*2 + i)*16 + xb)*33 + mt*16 + quad*4 + r] = vo[mt][i][r];
  __syncthreads();
  ln_reduce512(tile, red, tid);
  if (words[s] != 0) {
    const float g = LD(nfg, o, bf), b2 = LD(nfb, o, bf);
    bf16* fbd = (bf16*)(ws + OF_FEATB);
#pragma unroll
    for (int xi = 0; xi < 16; ++xi) {
      const int x = half*16 + xi;
      fbd[((size_t)(x & 15)*PP + p0 + (x >> 4))*CD + o] =
          f2bf((tile[o*33 + x] - red[1024 + x]) * red[1056 + x] * g + b2);
    }
  }
}

// output [n][c][p] from bf16 feat [n][p][c]
__global__ __launch_bounds__(256) void k_final(const float* __restrict__ ws, void* __restrict__ out) {
  const int bf = get_bf(ws);
  const size_t i = (size_t)blockIdx.x*256 + threadIdx.x;
  const int n = (int)(i >> 18), c = (int)((i >> 10) & 255), p = (int)(i & 1023);
  const bf16* fb = (const bf16*)(ws + OF_FEATB);
  float v = bf2f(fb[((size_t)(n*PP + p))*CD + c]);
  if (bf) ((bf16*)out)[i] = f2bf(v);
  else    ((float*)out)[i] = v;
}

extern "C" void kernel_launch(void* const* d_in, const int* in_sizes, int n_in,
                              void* d_out, int out_size, void* d_ws, size_t ws_size,
                              hipStream_t stream) {
  (void)in_sizes; (void)n_in; (void)out_size; (void)ws_size;
  const void* hn      = d_in[1];
  const void* feature = d_in[2];
  const void* emb     = d_in[3];
  const int*  words   = (const int*)d_in[4];
  const void* qw  = d_in[5];
  const void* qb  = d_in[6];
  const void* mw  = d_in[7];
  const void* mg  = d_in[8];
  const void* mb  = d_in[9];
  const void* ipw = d_in[10];
  const void* ipb = d_in[11];
  const void* opw = d_in[12];
  const void* opb = d_in[13];
  const void* ng  = d_in[14];
  const void* nb  = d_in[15];
  const void* l1w = d_in[16];
  const void* l1b = d_in[17];
  const void* l2w = d_in[18];
  const void* l2b = d_in[19];
  const void* nfg = d_in[20];
  const void* nfb = d_in[21];
  float* ws = (float*)d_ws;

  k_detect<<<1, 64, 0, stream>>>(mg, ws);
  k_init<<<NB*PP, 256, 0, stream>>>(feature, ws);
  k_qh<<<SEQL*NB, 256, 0, stream>>>(emb, qw, qb, ipw, ipb, ws);
  k_wregion<<<(9*CD*HND)/256, 256, 0, stream>>>(mw, ws);
  k_hnw<<<9*NB, 256, 0, stream>>>(hn, ws);
  k_sconv<<<PP, 256, 0, stream>>>(mw, ws);
  k_wpack<<<(9*8*16*64*8)/256, 256, 0, stream>>>(mw, ws);
  k_wpackB<<<(5*65536)/256, 256, 0, stream>>>(ipw, opw, l1w, l2w, ws);

  for (int s = 0; s < SEQL; ++s) {
    k_convkv<<<NB*32, 512, 0, stream>>>(mg, mb, ipb, ws);
    k_oplin<<<PP/2, 512, 0, stream>>>(ipb, opb, ng, nb, l1b, l2b, nfg, nfb, words, s, ws);
  }
  k_final<<<NB*CD*PP/256, 256, 0, stream>>>(ws, (void*)d_out);
}